// Round 10
// baseline (217.180 us; speedup 1.0000x reference)
//
#include <hip/hip_runtime.h>
#include <hip/hip_bf16.h>
#include <stdint.h>

// ---------- types ----------
typedef __attribute__((ext_vector_type(8))) short short8;      // 8 bf16 (MFMA A/B frag)
typedef __attribute__((ext_vector_type(4))) float floatx4;     // 16x16 C/D frag
typedef __attribute__((ext_vector_type(16))) float floatx16;   // 32x32 C/D frag
typedef __attribute__((ext_vector_type(4))) uint16_t ushort4v;

#define MFMA16(a, b, c) __builtin_amdgcn_mfma_f32_16x16x32_bf16((a), (b), (c), 0, 0, 0)
#define MFMA32(a, b, c) __builtin_amdgcn_mfma_f32_32x32x16_bf16((a), (b), (c), 0, 0, 0)

// async global->LDS, 16B per lane; LDS dest is wave-uniform base + lane*16
#define GLOAD_LDS16(g, l)                                                          \
  __builtin_amdgcn_global_load_lds(                                                \
      (const __attribute__((address_space(1))) uint32_t*)(g),                      \
      (__attribute__((address_space(3))) uint32_t*)(l), 16, 0, 0)

// packed f32x2 -> bf16x2
#define CVTPK(lo_, hi_, out_) \
  asm("v_cvt_pk_bf16_f32 %0, %1, %2" : "=v"(out_) : "v"(lo_), "v"(hi_))
// exchange a's high 32 lanes with b's low 32 lanes
#define SWAP32(a_, b_) \
  asm("v_permlane32_swap_b32 %0, %1" : "+v"(a_), "+v"(b_))

// fp32 -> bf16 round-to-nearest-even
__device__ __forceinline__ uint16_t f2bf(float x) {
  union { float f; uint32_t u; } c; c.f = x;
  return (uint16_t)((c.u + 0x7FFFu + ((c.u >> 16) & 1u)) >> 16);
}

// ---------- fp32 -> bf16 converts, z-batched ----------
__global__ void cvt3_k(const float* __restrict__ s0, const float* __restrict__ s1,
                       const float* __restrict__ s2, uint16_t* __restrict__ dst, int n4) {
  const float* src = blockIdx.z == 0 ? s0 : (blockIdx.z == 1 ? s1 : s2);
  uint16_t* d = dst + (size_t)blockIdx.z * 8388608;  // 16MB stride
  int stride = gridDim.x * blockDim.x;
  for (int i = blockIdx.x * blockDim.x + threadIdx.x; i < n4; i += stride) {
    float4 v = ((const float4*)src)[i];
    ushort4v o;
    o.x = f2bf(v.x); o.y = f2bf(v.y); o.z = f2bf(v.z); o.w = f2bf(v.w);
    ((ushort4v*)d)[i] = o;
  }
}
__global__ void cvt4_k(const float* __restrict__ s0, const float* __restrict__ s1,
                       const float* __restrict__ s2, const float* __restrict__ s3,
                       uint16_t* __restrict__ dst, int n4) {
  const float* src = blockIdx.z == 0 ? s0 : (blockIdx.z == 1 ? s1 : (blockIdx.z == 2 ? s2 : s3));
  uint16_t* d = dst + (size_t)blockIdx.z * 1048576;  // 2MB stride
  int stride = gridDim.x * blockDim.x;
  for (int i = blockIdx.x * blockDim.x + threadIdx.x; i < n4; i += stride) {
    float4 v = ((const float4*)src)[i];
    ushort4v o;
    o.x = f2bf(v.x); o.y = f2bf(v.y); o.z = f2bf(v.z); o.w = f2bf(v.w);
    ((ushort4v*)d)[i] = o;
  }
}

// ---------- GEMM body: C[8192,1024] = (A @ W^T + bias) * scale ----------
template <int OUT_BF16>
__device__ __forceinline__ void gemm_body(const uint16_t* __restrict__ A,
                                          const uint16_t* __restrict__ W,
                                          const float* __restrict__ bias,
                                          void* __restrict__ Cout, float scale) {
  constexpr int N = 1024, K = 1024;
  __shared__ uint16_t As[128 * 32];
  __shared__ uint16_t Bs[128 * 32];
  const int t = threadIdx.x;
  const int l = t & 63;
  const int w = t >> 6;
  const int wr = w >> 1, wc = w & 1;
  const int l16 = l & 15, lhi = l >> 4;
  const int brow = blockIdx.y * 128;
  const int bcol = blockIdx.x * 128;

  floatx4 acc[4][4] = {};

  for (int k0 = 0; k0 < K; k0 += 32) {
#pragma unroll
    for (int j = 0; j < 2; ++j) {
      int c = j * 256 + t;
      int row = c >> 2;
      int ko = (c & 3) * 8;
      const uint16_t* ga = A + (size_t)(brow + row) * K + k0 + ko;
      const uint16_t* gb = W + (size_t)(bcol + row) * K + k0 + ko;
      uint16_t* la = As + (size_t)(j * 256 + w * 64) * 8;
      uint16_t* lb = Bs + (size_t)(j * 256 + w * 64) * 8;
      GLOAD_LDS16(ga, la);
      GLOAD_LDS16(gb, lb);
    }
    __syncthreads();

    short8 a[4], b[4];
#pragma unroll
    for (int m = 0; m < 4; ++m)
      a[m] = *(const short8*)&As[(wr * 64 + m * 16 + l16) * 32 + lhi * 8];
#pragma unroll
    for (int n = 0; n < 4; ++n)
      b[n] = *(const short8*)&Bs[(wc * 64 + n * 16 + l16) * 32 + lhi * 8];
#pragma unroll
    for (int m = 0; m < 4; ++m)
#pragma unroll
      for (int n = 0; n < 4; ++n)
        acc[m][n] = MFMA16(a[m], b[n], acc[m][n]);
    __syncthreads();
  }

#pragma unroll
  for (int n = 0; n < 4; ++n) {
    int col = bcol + wc * 64 + n * 16 + l16;
    float bv = bias[col];
#pragma unroll
    for (int m = 0; m < 4; ++m) {
#pragma unroll
      for (int j = 0; j < 4; ++j) {
        int row = brow + wr * 64 + m * 16 + lhi * 4 + j;
        float v = (acc[m][n][j] + bv) * scale;
        if (OUT_BF16)
          ((uint16_t*)Cout)[(size_t)row * N + col] = f2bf(v);
        else
          ((float*)Cout)[(size_t)row * N + col] = v;
      }
    }
  }
}

// fused Q/K/V projections: blockIdx.z selects the projection
__global__ __launch_bounds__(256)
void gemm_qkv_k(const uint16_t* __restrict__ XQ, const uint16_t* __restrict__ XK,
                const uint16_t* __restrict__ XV, const uint16_t* __restrict__ WQ,
                const uint16_t* __restrict__ WK, const uint16_t* __restrict__ WV,
                const float* __restrict__ bq, const float* __restrict__ bk,
                const float* __restrict__ bv, uint16_t* __restrict__ QP,
                uint16_t* __restrict__ KP, uint16_t* __restrict__ VP, float qscale) {
  const uint16_t *A, *W; const float* bi; uint16_t* C; float sc;
  if (blockIdx.z == 0)      { A = XQ; W = WQ; bi = bq; C = QP; sc = qscale; }
  else if (blockIdx.z == 1) { A = XK; W = WK; bi = bk; C = KP; sc = 1.0f; }
  else                      { A = XV; W = WV; bi = bv; C = VP; sc = 1.0f; }
  gemm_body<1>(A, W, bi, C, sc);
}

__global__ __launch_bounds__(256)
void gemm_o_k(const uint16_t* __restrict__ A, const uint16_t* __restrict__ W,
              const float* __restrict__ bias, float* __restrict__ Cout) {
  gemm_body<0>(A, W, bias, Cout, 1.0f);
}

// ---------- V transpose: VP[b,s,h*64+d] -> VT[(b*16+h)*64+d][s] ----------
__global__ __launch_bounds__(256)
void vtrans_k(const uint16_t* __restrict__ VP, uint16_t* __restrict__ VT) {
  __shared__ uint16_t T[64][66];
  const int t = threadIdx.x;
  const int bh = blockIdx.y;
  const int s0 = blockIdx.x * 64;
  const int b = bh >> 4, h = bh & 15;
  const size_t src = ((size_t)b * 2048 + s0) * 1024 + (size_t)h * 64;
#pragma unroll
  for (int it = 0; it < 2; ++it) {
    int u = it * 256 + t;
    int s = u >> 3;
    int d0 = (u & 7) * 8;
    short8 v = *(const short8*)(VP + src + (size_t)s * 1024 + d0);
#pragma unroll
    for (int i = 0; i < 8; ++i) T[s][d0 + i] = (uint16_t)v[i];
  }
  __syncthreads();
  const size_t dst = (size_t)bh * 131072 + s0;  // row stride 2048
#pragma unroll
  for (int it = 0; it < 2; ++it) {
    int u = it * 256 + t;
    int d = u >> 3;
    int ss = (u & 7) * 8;
    union { uint16_t u16[8]; short8 s8; } pk;
#pragma unroll
    for (int i = 0; i < 8; ++i) pk.u16[i] = T[ss + i][d];
    *(short8*)(VT + dst + (size_t)d * 2048 + ss) = pk.s8;
  }
}

// ---------- flash attention: quarter-pipelined (QK_next ∥ exp/pack_cur) ----------
// 8 waves/block, shared K/V tiles, KVBLK=128 split into 4 quarters of 32 s.
// Software pipeline with named sfA/sfB (rule #20): the next quarter's QK MFMAs
// sit adjacent to the current quarter's exp/pack VALU -> scheduler fills both pipes.
__global__ __launch_bounds__(512, 2)
void attn_k(const uint16_t* __restrict__ Qp, const uint16_t* __restrict__ Kp,
            const uint16_t* __restrict__ Vt, uint16_t* __restrict__ AO) {
  __shared__ uint16_t Kl[2][64 * 128];   // 16KB per buffer
  __shared__ uint16_t Vl[2][64 * 128];   // 16KB per buffer

  const int t = threadIdx.x;
  const int l = t & 63, w = t >> 6;       // w = 0..7
  const int l32 = l & 31, hi = l >> 5;

  // XCD-chunked swizzle: 512 blocks, 64 per XCD -> 8 contiguous bh groups each.
  const int f = blockIdx.y * 8 + blockIdx.x;
  const int virt = (f & 7) * 64 + (f >> 3);
  const int vx = virt & 7;     // q-block (256 q each)
  const int vy = virt >> 3;    // bh

  const int q0 = vx * 256 + w * 32;
  const size_t base = (size_t)(vy >> 4) * 2048 * 1024 + (size_t)(vy & 15) * 64;
  const size_t vbg = (size_t)vy * 131072;  // (b*16+h)*64*2048

  union PAu { uint32_t u[4]; short8 s; };

  // staging: 1024 chunks per matrix per tile; 512 threads -> 2 issues each.
  const uint16_t* pK[2];
  const uint16_t* pV[2];
#pragma unroll
  for (int i = 0; i < 2; ++i) {
    int c = i * 512 + t;
    int r = c >> 4, qs = c & 15;
    int q0c = qs ^ (r & 15);
    pK[i] = Kp + base + (size_t)(64 * (q0c >> 3) + r) * 1024 + (q0c & 7) * 8;
    pV[i] = Vt + vbg + (size_t)r * 2048 + q0c * 8;
  }

#define STAGE_ALL(NB)                                                 \
  {                                                                   \
    _Pragma("unroll") for (int i = 0; i < 2; ++i) {                   \
      GLOAD_LDS16(pK[i], &Kl[NB][(size_t)(i * 512 + w * 64) * 8]);    \
      GLOAD_LDS16(pV[i], &Vl[NB][(size_t)(i * 512 + w * 64) * 8]);    \
      pK[i] += 131072;  /* +128 source rows */                        \
      pV[i] += 128;     /* +128 s columns  */                        \
    }                                                                 \
  }

  // Q B-frags: lane holds Q[q0 + l32][k = ks*16 + hi*8 + i]
  short8 qf[4];
#pragma unroll
  for (int ks = 0; ks < 4; ++ks)
    qf[ks] = *(const short8*)(Qp + base + (size_t)(q0 + l32) * 1024 + ks * 16 + hi * 8);

  floatx16 of0 = {}, of1 = {};   // O[q][d] C-frags
  float rs = 0.f;                // per-lane partial rowsum

  const int swzb = (l32 & 15);
  const int krow = l32 * 256;    // byte base of LDS row l32 (row +32 = +8192)

  STAGE_ALL(0);
  __syncthreads();

  // quarter (H, RH): s-range [H*64 + RH*32, +32). Identical operand mapping to
  // the R8 HALF split, reordered for MFMA/VALU interleave.
#define QK_Q(SF, CUR, H, RH)                                                          \
  {                                                                                   \
    _Pragma("unroll") for (int ks = 0; ks < 4; ++ks) {                                \
      int kbyte = krow + (RH) * 8192 + ((((H) * 8 + 2 * ks + hi) ^ swzb) << 4);       \
      short8 kf = *(const short8*)((char*)Kl[CUR] + kbyte);                           \
      SF = MFMA32(kf, qf[ks], SF);                                                    \
    }                                                                                 \
  }

#define EXPPACK(SF, P0, P1)                                                           \
  {                                                                                   \
    _Pragma("unroll") for (int r = 0; r < 16; ++r) {                                  \
      SF[r] = __builtin_amdgcn_exp2f(SF[r]);                                          \
      rs += SF[r];                                                                    \
    }                                                                                 \
    uint32_t a0, a1, b0, b1;                                                          \
    CVTPK(SF[0], SF[1], a0); CVTPK(SF[2], SF[3], a1);                                 \
    CVTPK(SF[4], SF[5], b0); CVTPK(SF[6], SF[7], b1);                                 \
    SWAP32(a0, b0); SWAP32(a1, b1);                                                   \
    P0.u[0] = a0; P0.u[1] = a1; P0.u[2] = b0; P0.u[3] = b1;                           \
    CVTPK(SF[8], SF[9], a0); CVTPK(SF[10], SF[11], a1);                               \
    CVTPK(SF[12], SF[13], b0); CVTPK(SF[14], SF[15], b1);                             \
    SWAP32(a0, b0); SWAP32(a1, b1);                                                   \
    P1.u[0] = a0; P1.u[1] = a1; P1.u[2] = b0; P1.u[3] = b1;                           \
  }

#define PV_Q(P0, P1, CUR, H, RH)                                                      \
  {                                                                                   \
    int vb0 = krow + ((((H) * 8 + 2 * (2 * (RH)) + hi) ^ swzb) << 4);                 \
    int vb1 = krow + ((((H) * 8 + 2 * (2 * (RH) + 1) + hi) ^ swzb) << 4);             \
    short8 vf00 = *(const short8*)((char*)Vl[CUR] + vb0);                             \
    short8 vf01 = *(const short8*)((char*)Vl[CUR] + vb0 + 8192);                      \
    short8 vf10 = *(const short8*)((char*)Vl[CUR] + vb1);                             \
    short8 vf11 = *(const short8*)((char*)Vl[CUR] + vb1 + 8192);                      \
    of0 = MFMA32(P0.s, vf00, of0);                                                    \
    of1 = MFMA32(P0.s, vf01, of1);                                                    \
    of0 = MFMA32(P1.s, vf10, of0);                                                    \
    of1 = MFMA32(P1.s, vf11, of1);                                                    \
  }

#define STEP128(CUR, PF)                                                              \
  {                                                                                   \
    if (PF) STAGE_ALL(CUR ^ 1);                                                       \
    floatx16 sfA = {}, sfB = {};                                                      \
    QK_Q(sfA, CUR, 0, 0);                       /* q0 scores */                       \
    QK_Q(sfB, CUR, 0, 1);                       /* q1 QK ∥ q0 exp/pack below */       \
    {                                                                                 \
      PAu p0, p1;                                                                     \
      EXPPACK(sfA, p0, p1);                                                           \
      PV_Q(p0, p1, CUR, 0, 0);                                                        \
    }                                                                                 \
    sfA = (floatx16){};                                                               \
    QK_Q(sfA, CUR, 1, 0);                       /* q2 QK ∥ q1 exp/pack */             \
    {                                                                                 \
      PAu p0, p1;                                                                     \
      EXPPACK(sfB, p0, p1);                                                           \
      PV_Q(p0, p1, CUR, 0, 1);                                                        \
    }                                                                                 \
    sfB = (floatx16){};                                                               \
    QK_Q(sfB, CUR, 1, 1);                       /* q3 QK ∥ q2 exp/pack */             \
    {                                                                                 \
      PAu p0, p1;                                                                     \
      EXPPACK(sfA, p0, p1);                                                           \
      PV_Q(p0, p1, CUR, 1, 0);                                                        \
    }                                                                                 \
    {                                                                                 \
      PAu p0, p1;                                                                     \
      EXPPACK(sfB, p0, p1);                                                           \
      PV_Q(p0, p1, CUR, 1, 1);                                                        \
    }                                                                                 \
    __syncthreads();                                                                  \
  }

  for (int it = 0; it < 8; ++it) {   // 16 kv-tiles of 128, 2 per iteration
    STEP128(0, 1);
    STEP128(1, it < 7);
  }

  // --- epilogue: complete rowsums and normalize.
  rs += __shfl_xor(rs, 32);          // full rowsum for q = l32 (both hi halves)
#pragma unroll
  for (int r = 0; r < 16; ++r) {
    int qloc = (r & 3) + 8 * (r >> 2) + 4 * hi;       // q index of of-frag row r
    float rsq = __shfl(rs, qloc);                      // rowsum for that q
    float rinv = 1.0f / rsq;
    int qrow = q0 + qloc;
    AO[base + (size_t)qrow * 1024 + l32]      = f2bf(of0[r] * rinv);
    AO[base + (size_t)qrow * 1024 + 32 + l32] = f2bf(of1[r] * rinv);
  }
#undef STAGE_ALL
#undef QK_Q
#undef EXPPACK
#undef PV_Q
#undef STEP128
}

// ---------- launch ----------
extern "C" void kernel_launch(void* const* d_in, const int* in_sizes, int n_in,
                              void* d_out, int out_size, void* d_ws, size_t ws_size,
                              hipStream_t stream) {
  const float* q  = (const float*)d_in[0];
  const float* k  = (const float*)d_in[1];
  const float* v  = (const float*)d_in[2];
  const float* Wq = (const float*)d_in[3];
  const float* bq = (const float*)d_in[4];
  const float* Wk = (const float*)d_in[5];
  const float* bk = (const float*)d_in[6];
  const float* Wv = (const float*)d_in[7];
  const float* bv = (const float*)d_in[8];
  const float* Wo = (const float*)d_in[9];
  const float* bo = (const float*)d_in[10];

  const size_t MB = 1ull << 20;
  char* ws = (char*)d_ws;
  uint16_t* XQ  = (uint16_t*)(ws + 0 * MB);    // 16MB x3, contiguous (cvt3 strides)
  uint16_t* XK  = (uint16_t*)(ws + 16 * MB);
  uint16_t* XV  = (uint16_t*)(ws + 32 * MB);
  uint16_t* WQb = (uint16_t*)(ws + 48 * MB);   // 2MB x4, contiguous (cvt4 strides)
  uint16_t* WKb = (uint16_t*)(ws + 50 * MB);
  uint16_t* WVb = (uint16_t*)(ws + 52 * MB);
  uint16_t* WOb = (uint16_t*)(ws + 54 * MB);
  uint16_t* QP  = (uint16_t*)(ws + 56 * MB);
  uint16_t* KP  = (uint16_t*)(ws + 72 * MB);
  uint16_t* VP  = (uint16_t*)(ws + 88 * MB);
  uint16_t* AO  = XQ;   // alias: XQ dead after QKV projection
  uint16_t* VT  = XK;   // alias: XK dead after QKV projection (16MB: 64 heads x 64 x 2048)

  const int NTOK = 4 * 2048;
  const int D = 1024;
  const int nBig = NTOK * D / 4;  // 2M float4
  const int nW = D * D / 4;       // 256K float4
  const float qscale = 0.125f * 1.4426950408889634f;  // softmax scale * log2e -> exp2

  cvt3_k<<<dim3(2048, 1, 3), dim3(256), 0, stream>>>(q, k, v, XQ, nBig);
  cvt4_k<<<dim3(1024, 1, 4), dim3(256), 0, stream>>>(Wq, Wk, Wv, Wo, WQb, nW);

  gemm_qkv_k<<<dim3(D / 128, NTOK / 128, 3), dim3(256), 0, stream>>>(
      XQ, XK, XV, WQb, WKb, WVb, bq, bk, bv, QP, KP, VP, qscale);

  vtrans_k<<<dim3(32, 64), dim3(256), 0, stream>>>(VP, VT);

  attn_k<<<dim3(8, 64), dim3(512), 0, stream>>>(QP, KP, VT, AO);

  gemm_o_k<<<dim3(D / 128, NTOK / 128), dim3(256), 0, stream>>>(AO, WOb, bo, (float*)d_out);
}

// Round 11
// 203.342 us; speedup vs baseline: 1.0681x; 1.0681x over previous
//
#include <hip/hip_runtime.h>
#include <hip/hip_bf16.h>
#include <stdint.h>

// ---------- types ----------
typedef __attribute__((ext_vector_type(8))) short short8;      // 8 bf16 (MFMA A/B frag)
typedef __attribute__((ext_vector_type(4))) float floatx4;     // 16x16 C/D frag
typedef __attribute__((ext_vector_type(16))) float floatx16;   // 32x32 C/D frag
typedef __attribute__((ext_vector_type(4))) uint16_t ushort4v;

#define MFMA16(a, b, c) __builtin_amdgcn_mfma_f32_16x16x32_bf16((a), (b), (c), 0, 0, 0)
#define MFMA32(a, b, c) __builtin_amdgcn_mfma_f32_32x32x16_bf16((a), (b), (c), 0, 0, 0)

// async global->LDS, 16B per lane; LDS dest is wave-uniform base + lane*16
#define GLOAD_LDS16(g, l)                                                          \
  __builtin_amdgcn_global_load_lds(                                                \
      (const __attribute__((address_space(1))) uint32_t*)(g),                      \
      (__attribute__((address_space(3))) uint32_t*)(l), 16, 0, 0)

// packed f32x2 -> bf16x2
#define CVTPK(lo_, hi_, out_) \
  asm("v_cvt_pk_bf16_f32 %0, %1, %2" : "=v"(out_) : "v"(lo_), "v"(hi_))
// exchange a's high 32 lanes with b's low 32 lanes
#define SWAP32(a_, b_) \
  asm("v_permlane32_swap_b32 %0, %1" : "+v"(a_), "+v"(b_))

// fp32 -> bf16 round-to-nearest-even
__device__ __forceinline__ uint16_t f2bf(float x) {
  union { float f; uint32_t u; } c; c.f = x;
  return (uint16_t)((c.u + 0x7FFFu + ((c.u >> 16) & 1u)) >> 16);
}

// ---------- fp32 -> bf16 converts, z-batched ----------
__global__ void cvt3_k(const float* __restrict__ s0, const float* __restrict__ s1,
                       const float* __restrict__ s2, uint16_t* __restrict__ dst, int n4) {
  const float* src = blockIdx.z == 0 ? s0 : (blockIdx.z == 1 ? s1 : s2);
  uint16_t* d = dst + (size_t)blockIdx.z * 8388608;  // 16MB stride
  int stride = gridDim.x * blockDim.x;
  for (int i = blockIdx.x * blockDim.x + threadIdx.x; i < n4; i += stride) {
    float4 v = ((const float4*)src)[i];
    ushort4v o;
    o.x = f2bf(v.x); o.y = f2bf(v.y); o.z = f2bf(v.z); o.w = f2bf(v.w);
    ((ushort4v*)d)[i] = o;
  }
}
__global__ void cvt4_k(const float* __restrict__ s0, const float* __restrict__ s1,
                       const float* __restrict__ s2, const float* __restrict__ s3,
                       uint16_t* __restrict__ dst, int n4) {
  const float* src = blockIdx.z == 0 ? s0 : (blockIdx.z == 1 ? s1 : (blockIdx.z == 2 ? s2 : s3));
  uint16_t* d = dst + (size_t)blockIdx.z * 1048576;  // 2MB stride
  int stride = gridDim.x * blockDim.x;
  for (int i = blockIdx.x * blockDim.x + threadIdx.x; i < n4; i += stride) {
    float4 v = ((const float4*)src)[i];
    ushort4v o;
    o.x = f2bf(v.x); o.y = f2bf(v.y); o.z = f2bf(v.z); o.w = f2bf(v.w);
    ((ushort4v*)d)[i] = o;
  }
}

// ---------- GEMM body: C[8192,1024] = (A @ W^T + bias) * scale ----------
// brow/bcol passed in (caller applies XCD-chunked block swizzle).
template <int OUT_BF16>
__device__ __forceinline__ void gemm_body(const uint16_t* __restrict__ A,
                                          const uint16_t* __restrict__ W,
                                          const float* __restrict__ bias,
                                          void* __restrict__ Cout, float scale,
                                          int brow, int bcol) {
  constexpr int N = 1024, K = 1024;
  __shared__ uint16_t As[128 * 32];
  __shared__ uint16_t Bs[128 * 32];
  const int t = threadIdx.x;
  const int l = t & 63;
  const int w = t >> 6;
  const int wr = w >> 1, wc = w & 1;
  const int l16 = l & 15, lhi = l >> 4;

  floatx4 acc[4][4] = {};

  for (int k0 = 0; k0 < K; k0 += 32) {
#pragma unroll
    for (int j = 0; j < 2; ++j) {
      int c = j * 256 + t;
      int row = c >> 2;
      int ko = (c & 3) * 8;
      const uint16_t* ga = A + (size_t)(brow + row) * K + k0 + ko;
      const uint16_t* gb = W + (size_t)(bcol + row) * K + k0 + ko;
      uint16_t* la = As + (size_t)(j * 256 + w * 64) * 8;
      uint16_t* lb = Bs + (size_t)(j * 256 + w * 64) * 8;
      GLOAD_LDS16(ga, la);
      GLOAD_LDS16(gb, lb);
    }
    __syncthreads();

    short8 a[4], b[4];
#pragma unroll
    for (int m = 0; m < 4; ++m)
      a[m] = *(const short8*)&As[(wr * 64 + m * 16 + l16) * 32 + lhi * 8];
#pragma unroll
    for (int n = 0; n < 4; ++n)
      b[n] = *(const short8*)&Bs[(wc * 64 + n * 16 + l16) * 32 + lhi * 8];
#pragma unroll
    for (int m = 0; m < 4; ++m)
#pragma unroll
      for (int n = 0; n < 4; ++n)
        acc[m][n] = MFMA16(a[m], b[n], acc[m][n]);
    __syncthreads();
  }

#pragma unroll
  for (int n = 0; n < 4; ++n) {
    int col = bcol + wc * 64 + n * 16 + l16;
    float bv = bias[col];
#pragma unroll
    for (int m = 0; m < 4; ++m) {
#pragma unroll
      for (int j = 0; j < 4; ++j) {
        int row = brow + wr * 64 + m * 16 + lhi * 4 + j;
        float v = (acc[m][n][j] + bv) * scale;
        if (OUT_BF16)
          ((uint16_t*)Cout)[(size_t)row * N + col] = f2bf(v);
        else
          ((float*)Cout)[(size_t)row * N + col] = v;
      }
    }
  }
}

// fused Q/K/V projections with XCD-chunked swizzle.
// 1536 blocks; f -> virt = (f&7)*192 + f>>3: each XCD owns 24 complete (z,y)
// A-panel groups (all 8 x-blocks) -> A fetched once per panel, W reused 24x.
__global__ __launch_bounds__(256)
void gemm_qkv_k(const uint16_t* __restrict__ XQ, const uint16_t* __restrict__ XK,
                const uint16_t* __restrict__ XV, const uint16_t* __restrict__ WQ,
                const uint16_t* __restrict__ WK, const uint16_t* __restrict__ WV,
                const float* __restrict__ bq, const float* __restrict__ bk,
                const float* __restrict__ bv, uint16_t* __restrict__ QP,
                uint16_t* __restrict__ KP, uint16_t* __restrict__ VP, float qscale) {
  const int f = (blockIdx.z * 64 + blockIdx.y) * 8 + blockIdx.x;
  const int virt = (f & 7) * 192 + (f >> 3);
  const int vz = virt >> 9;            // /512
  const int vy = (virt & 511) >> 3;
  const int vx = virt & 7;

  const uint16_t *A, *W; const float* bi; uint16_t* C; float sc;
  if (vz == 0)      { A = XQ; W = WQ; bi = bq; C = QP; sc = qscale; }
  else if (vz == 1) { A = XK; W = WK; bi = bk; C = KP; sc = 1.0f; }
  else              { A = XV; W = WV; bi = bv; C = VP; sc = 1.0f; }
  gemm_body<1>(A, W, bi, C, sc, vy * 128, vx * 128);
}

// output projection, 512 blocks: virt = (f&7)*64 + f>>3 -> 8 y-groups per XCD.
__global__ __launch_bounds__(256)
void gemm_o_k(const uint16_t* __restrict__ A, const uint16_t* __restrict__ W,
              const float* __restrict__ bias, float* __restrict__ Cout) {
  const int f = blockIdx.y * 8 + blockIdx.x;
  const int virt = (f & 7) * 64 + (f >> 3);
  const int vy = virt >> 3;
  const int vx = virt & 7;
  gemm_body<0>(A, W, bias, Cout, 1.0f, vy * 128, vx * 128);
}

// ---------- V transpose: VP[b,s,h*64+d] -> VT[(b*16+h)*64+d][s] ----------
__global__ __launch_bounds__(256)
void vtrans_k(const uint16_t* __restrict__ VP, uint16_t* __restrict__ VT) {
  __shared__ uint16_t T[64][66];
  const int t = threadIdx.x;
  const int bh = blockIdx.y;
  const int s0 = blockIdx.x * 64;
  const int b = bh >> 4, h = bh & 15;
  const size_t src = ((size_t)b * 2048 + s0) * 1024 + (size_t)h * 64;
#pragma unroll
  for (int it = 0; it < 2; ++it) {
    int u = it * 256 + t;
    int s = u >> 3;
    int d0 = (u & 7) * 8;
    short8 v = *(const short8*)(VP + src + (size_t)s * 1024 + d0);
#pragma unroll
    for (int i = 0; i < 8; ++i) T[s][d0 + i] = (uint16_t)v[i];
  }
  __syncthreads();
  const size_t dst = (size_t)bh * 131072 + s0;  // row stride 2048
#pragma unroll
  for (int it = 0; it < 2; ++it) {
    int u = it * 256 + t;
    int d = u >> 3;
    int ss = (u & 7) * 8;
    union { uint16_t u16[8]; short8 s8; } pk;
#pragma unroll
    for (int i = 0; i < 8; ++i) pk.u16[i] = T[ss + i][d];
    *(short8*)(VT + dst + (size_t)d * 2048 + ss) = pk.s8;
  }
}

// ---------- flash attention: quarter-pipelined (QK_next ∥ exp/pack_cur) ----------
__global__ __launch_bounds__(512, 2)
void attn_k(const uint16_t* __restrict__ Qp, const uint16_t* __restrict__ Kp,
            const uint16_t* __restrict__ Vt, uint16_t* __restrict__ AO) {
  __shared__ uint16_t Kl[2][64 * 128];   // 16KB per buffer
  __shared__ uint16_t Vl[2][64 * 128];   // 16KB per buffer

  const int t = threadIdx.x;
  const int l = t & 63, w = t >> 6;       // w = 0..7
  const int l32 = l & 31, hi = l >> 5;

  // XCD-chunked swizzle: 512 blocks, 64 per XCD -> 8 contiguous bh groups each.
  const int f = blockIdx.y * 8 + blockIdx.x;
  const int virt = (f & 7) * 64 + (f >> 3);
  const int vx = virt & 7;     // q-block (256 q each)
  const int vy = virt >> 3;    // bh

  const int q0 = vx * 256 + w * 32;
  const size_t base = (size_t)(vy >> 4) * 2048 * 1024 + (size_t)(vy & 15) * 64;
  const size_t vbg = (size_t)vy * 131072;  // (b*16+h)*64*2048

  union PAu { uint32_t u[4]; short8 s; };

  // staging: 1024 chunks per matrix per tile; 512 threads -> 2 issues each.
  const uint16_t* pK[2];
  const uint16_t* pV[2];
#pragma unroll
  for (int i = 0; i < 2; ++i) {
    int c = i * 512 + t;
    int r = c >> 4, qs = c & 15;
    int q0c = qs ^ (r & 15);
    pK[i] = Kp + base + (size_t)(64 * (q0c >> 3) + r) * 1024 + (q0c & 7) * 8;
    pV[i] = Vt + vbg + (size_t)r * 2048 + q0c * 8;
  }

#define STAGE_ALL(NB)                                                 \
  {                                                                   \
    _Pragma("unroll") for (int i = 0; i < 2; ++i) {                   \
      GLOAD_LDS16(pK[i], &Kl[NB][(size_t)(i * 512 + w * 64) * 8]);    \
      GLOAD_LDS16(pV[i], &Vl[NB][(size_t)(i * 512 + w * 64) * 8]);    \
      pK[i] += 131072;  /* +128 source rows */                        \
      pV[i] += 128;     /* +128 s columns  */                        \
    }                                                                 \
  }

  // Q B-frags: lane holds Q[q0 + l32][k = ks*16 + hi*8 + i]
  short8 qf[4];
#pragma unroll
  for (int ks = 0; ks < 4; ++ks)
    qf[ks] = *(const short8*)(Qp + base + (size_t)(q0 + l32) * 1024 + ks * 16 + hi * 8);

  floatx16 of0 = {}, of1 = {};   // O[q][d] C-frags
  float rs = 0.f;                // per-lane partial rowsum

  const int swzb = (l32 & 15);
  const int krow = l32 * 256;    // byte base of LDS row l32 (row +32 = +8192)

  STAGE_ALL(0);
  __syncthreads();

#define QK_Q(SF, CUR, H, RH)                                                          \
  {                                                                                   \
    _Pragma("unroll") for (int ks = 0; ks < 4; ++ks) {                                \
      int kbyte = krow + (RH) * 8192 + ((((H) * 8 + 2 * ks + hi) ^ swzb) << 4);       \
      short8 kf = *(const short8*)((char*)Kl[CUR] + kbyte);                           \
      SF = MFMA32(kf, qf[ks], SF);                                                    \
    }                                                                                 \
  }

#define EXPPACK(SF, P0, P1)                                                           \
  {                                                                                   \
    _Pragma("unroll") for (int r = 0; r < 16; ++r) {                                  \
      SF[r] = __builtin_amdgcn_exp2f(SF[r]);                                          \
      rs += SF[r];                                                                    \
    }                                                                                 \
    uint32_t a0, a1, b0, b1;                                                          \
    CVTPK(SF[0], SF[1], a0); CVTPK(SF[2], SF[3], a1);                                 \
    CVTPK(SF[4], SF[5], b0); CVTPK(SF[6], SF[7], b1);                                 \
    SWAP32(a0, b0); SWAP32(a1, b1);                                                   \
    P0.u[0] = a0; P0.u[1] = a1; P0.u[2] = b0; P0.u[3] = b1;                           \
    CVTPK(SF[8], SF[9], a0); CVTPK(SF[10], SF[11], a1);                               \
    CVTPK(SF[12], SF[13], b0); CVTPK(SF[14], SF[15], b1);                             \
    SWAP32(a0, b0); SWAP32(a1, b1);                                                   \
    P1.u[0] = a0; P1.u[1] = a1; P1.u[2] = b0; P1.u[3] = b1;                           \
  }

#define PV_Q(P0, P1, CUR, H, RH)                                                      \
  {                                                                                   \
    int vb0 = krow + ((((H) * 8 + 2 * (2 * (RH)) + hi) ^ swzb) << 4);                 \
    int vb1 = krow + ((((H) * 8 + 2 * (2 * (RH) + 1) + hi) ^ swzb) << 4);             \
    short8 vf00 = *(const short8*)((char*)Vl[CUR] + vb0);                             \
    short8 vf01 = *(const short8*)((char*)Vl[CUR] + vb0 + 8192);                      \
    short8 vf10 = *(const short8*)((char*)Vl[CUR] + vb1);                             \
    short8 vf11 = *(const short8*)((char*)Vl[CUR] + vb1 + 8192);                      \
    of0 = MFMA32(P0.s, vf00, of0);                                                    \
    of1 = MFMA32(P0.s, vf01, of1);                                                    \
    of0 = MFMA32(P1.s, vf10, of0);                                                    \
    of1 = MFMA32(P1.s, vf11, of1);                                                    \
  }

#define STEP128(CUR, PF)                                                              \
  {                                                                                   \
    if (PF) STAGE_ALL(CUR ^ 1);                                                       \
    floatx16 sfA = {}, sfB = {};                                                      \
    QK_Q(sfA, CUR, 0, 0);                                                             \
    QK_Q(sfB, CUR, 0, 1);                                                             \
    {                                                                                 \
      PAu p0, p1;                                                                     \
      EXPPACK(sfA, p0, p1);                                                           \
      PV_Q(p0, p1, CUR, 0, 0);                                                        \
    }                                                                                 \
    sfA = (floatx16){};                                                               \
    QK_Q(sfA, CUR, 1, 0);                                                             \
    {                                                                                 \
      PAu p0, p1;                                                                     \
      EXPPACK(sfB, p0, p1);                                                           \
      PV_Q(p0, p1, CUR, 0, 1);                                                        \
    }                                                                                 \
    sfB = (floatx16){};                                                               \
    QK_Q(sfB, CUR, 1, 1);                                                             \
    {                                                                                 \
      PAu p0, p1;                                                                     \
      EXPPACK(sfA, p0, p1);                                                           \
      PV_Q(p0, p1, CUR, 1, 0);                                                        \
    }                                                                                 \
    {                                                                                 \
      PAu p0, p1;                                                                     \
      EXPPACK(sfB, p0, p1);                                                           \
      PV_Q(p0, p1, CUR, 1, 1);                                                        \
    }                                                                                 \
    __syncthreads();                                                                  \
  }

  for (int it = 0; it < 8; ++it) {   // 16 kv-tiles of 128, 2 per iteration
    STEP128(0, 1);
    STEP128(1, it < 7);
  }

  // --- epilogue: complete rowsums and normalize.
  rs += __shfl_xor(rs, 32);          // full rowsum for q = l32 (both hi halves)
#pragma unroll
  for (int r = 0; r < 16; ++r) {
    int qloc = (r & 3) + 8 * (r >> 2) + 4 * hi;       // q index of of-frag row r
    float rsq = __shfl(rs, qloc);                      // rowsum for that q
    float rinv = 1.0f / rsq;
    int qrow = q0 + qloc;
    AO[base + (size_t)qrow * 1024 + l32]      = f2bf(of0[r] * rinv);
    AO[base + (size_t)qrow * 1024 + 32 + l32] = f2bf(of1[r] * rinv);
  }
#undef STAGE_ALL
#undef QK_Q
#undef EXPPACK
#undef PV_Q
#undef STEP128
}

// ---------- launch ----------
extern "C" void kernel_launch(void* const* d_in, const int* in_sizes, int n_in,
                              void* d_out, int out_size, void* d_ws, size_t ws_size,
                              hipStream_t stream) {
  const float* q  = (const float*)d_in[0];
  const float* k  = (const float*)d_in[1];
  const float* v  = (const float*)d_in[2];
  const float* Wq = (const float*)d_in[3];
  const float* bq = (const float*)d_in[4];
  const float* Wk = (const float*)d_in[5];
  const float* bk = (const float*)d_in[6];
  const float* Wv = (const float*)d_in[7];
  const float* bv = (const float*)d_in[8];
  const float* Wo = (const float*)d_in[9];
  const float* bo = (const float*)d_in[10];

  const size_t MB = 1ull << 20;
  char* ws = (char*)d_ws;
  uint16_t* XQ  = (uint16_t*)(ws + 0 * MB);    // 16MB x3, contiguous (cvt3 strides)
  uint16_t* XK  = (uint16_t*)(ws + 16 * MB);
  uint16_t* XV  = (uint16_t*)(ws + 32 * MB);
  uint16_t* WQb = (uint16_t*)(ws + 48 * MB);   // 2MB x4, contiguous (cvt4 strides)
  uint16_t* WKb = (uint16_t*)(ws + 50 * MB);
  uint16_t* WVb = (uint16_t*)(ws + 52 * MB);
  uint16_t* WOb = (uint16_t*)(ws + 54 * MB);
  uint16_t* QP  = (uint16_t*)(ws + 56 * MB);
  uint16_t* KP  = (uint16_t*)(ws + 72 * MB);
  uint16_t* VP  = (uint16_t*)(ws + 88 * MB);
  uint16_t* AO  = XQ;   // alias: XQ dead after QKV projection
  uint16_t* VT  = XK;   // alias: XK dead after QKV projection (16MB: 64 heads x 64 x 2048)

  const int NTOK = 4 * 2048;
  const int D = 1024;
  const int nBig = NTOK * D / 4;  // 2M float4
  const int nW = D * D / 4;       // 256K float4
  const float qscale = 0.125f * 1.4426950408889634f;  // softmax scale * log2e -> exp2

  cvt3_k<<<dim3(2048, 1, 3), dim3(256), 0, stream>>>(q, k, v, XQ, nBig);
  cvt4_k<<<dim3(1024, 1, 4), dim3(256), 0, stream>>>(Wq, Wk, Wv, Wo, WQb, nW);

  gemm_qkv_k<<<dim3(D / 128, NTOK / 128, 3), dim3(256), 0, stream>>>(
      XQ, XK, XV, WQb, WKb, WVb, bq, bk, bv, QP, KP, VP, qscale);

  vtrans_k<<<dim3(32, 64), dim3(256), 0, stream>>>(VP, VT);

  attn_k<<<dim3(8, 64), dim3(512), 0, stream>>>(QP, KP, VT, AO);

  gemm_o_k<<<dim3(D / 128, NTOK / 128), dim3(256), 0, stream>>>(AO, WOb, bo, (float*)d_out);
}

// Round 12
// 196.663 us; speedup vs baseline: 1.1043x; 1.0340x over previous
//
#include <hip/hip_runtime.h>
#include <hip/hip_bf16.h>
#include <stdint.h>

// ---------- types ----------
typedef __attribute__((ext_vector_type(8))) short short8;      // 8 bf16 (MFMA A/B frag)
typedef __attribute__((ext_vector_type(4))) float floatx4;     // 16x16 C/D frag
typedef __attribute__((ext_vector_type(16))) float floatx16;   // 32x32 C/D frag
typedef __attribute__((ext_vector_type(4))) uint16_t ushort4v;

#define MFMA16(a, b, c) __builtin_amdgcn_mfma_f32_16x16x32_bf16((a), (b), (c), 0, 0, 0)
#define MFMA32(a, b, c) __builtin_amdgcn_mfma_f32_32x32x16_bf16((a), (b), (c), 0, 0, 0)

// async global->LDS, 16B per lane; LDS dest is wave-uniform base + lane*16
#define GLOAD_LDS16(g, l)                                                          \
  __builtin_amdgcn_global_load_lds(                                                \
      (const __attribute__((address_space(1))) uint32_t*)(g),                      \
      (__attribute__((address_space(3))) uint32_t*)(l), 16, 0, 0)

// packed f32x2 -> bf16x2
#define CVTPK(lo_, hi_, out_) \
  asm("v_cvt_pk_bf16_f32 %0, %1, %2" : "=v"(out_) : "v"(lo_), "v"(hi_))
// exchange a's high 32 lanes with b's low 32 lanes
#define SWAP32(a_, b_) \
  asm("v_permlane32_swap_b32 %0, %1" : "+v"(a_), "+v"(b_))

// fp32 -> bf16 round-to-nearest-even
__device__ __forceinline__ uint16_t f2bf(float x) {
  union { float f; uint32_t u; } c; c.f = x;
  return (uint16_t)((c.u + 0x7FFFu + ((c.u >> 16) & 1u)) >> 16);
}

// ---------- fp32 -> bf16 converts, z-batched ----------
__global__ void cvt3_k(const float* __restrict__ s0, const float* __restrict__ s1,
                       const float* __restrict__ s2, uint16_t* __restrict__ dst, int n4) {
  const float* src = blockIdx.z == 0 ? s0 : (blockIdx.z == 1 ? s1 : s2);
  uint16_t* d = dst + (size_t)blockIdx.z * 8388608;  // 16MB stride
  int stride = gridDim.x * blockDim.x;
  for (int i = blockIdx.x * blockDim.x + threadIdx.x; i < n4; i += stride) {
    float4 v = ((const float4*)src)[i];
    ushort4v o;
    o.x = f2bf(v.x); o.y = f2bf(v.y); o.z = f2bf(v.z); o.w = f2bf(v.w);
    ((ushort4v*)d)[i] = o;
  }
}
__global__ void cvt4_k(const float* __restrict__ s0, const float* __restrict__ s1,
                       const float* __restrict__ s2, const float* __restrict__ s3,
                       uint16_t* __restrict__ dst, int n4) {
  const float* src = blockIdx.z == 0 ? s0 : (blockIdx.z == 1 ? s1 : (blockIdx.z == 2 ? s2 : s3));
  uint16_t* d = dst + (size_t)blockIdx.z * 1048576;  // 2MB stride
  int stride = gridDim.x * blockDim.x;
  for (int i = blockIdx.x * blockDim.x + threadIdx.x; i < n4; i += stride) {
    float4 v = ((const float4*)src)[i];
    ushort4v o;
    o.x = f2bf(v.x); o.y = f2bf(v.y); o.z = f2bf(v.z); o.w = f2bf(v.w);
    ((ushort4v*)d)[i] = o;
  }
}

// ---------- GEMM body: C[8192,1024] = (A @ W^T + bias) * scale ----------
// MODE: 0 = f32 row-major out, 1 = bf16 row-major out, 2 = bf16 V-transposed out
// (VT[(b*16+h)*64+d][s], packed 4-wide along s).
// LDS tiles: [32 rows][16 slots of 16B], slot q of row r holds chunk q^(r&15)
// (chunk c: arow = 32*(q0>>2) + r, kchunk = q0&3) -> frag reads conflict-free.
template <int MODE>
__device__ __forceinline__ void gemm_body(const uint16_t* __restrict__ A,
                                          const uint16_t* __restrict__ W,
                                          const float* __restrict__ bias,
                                          void* __restrict__ Cout, float scale,
                                          int brow, int bcol) {
  constexpr int N = 1024, K = 1024;
  __shared__ uint16_t As[32 * 128];   // 8KB, 256B rows
  __shared__ uint16_t Bs[32 * 128];
  const int t = threadIdx.x;
  const int l = t & 63;
  const int w = t >> 6;
  const int wr = w >> 1, wc = w & 1;
  const int l16 = l & 15, lhi = l >> 4;

  floatx4 acc[4][4] = {};

  for (int k0 = 0; k0 < K; k0 += 32) {
#pragma unroll
    for (int j = 0; j < 2; ++j) {
      int c = j * 256 + t;
      int r = c >> 4, qs = c & 15;
      int q0 = qs ^ (r & 15);
      int arow = 32 * (q0 >> 2) + r;
      int ko = (q0 & 3) * 8;
      const uint16_t* ga = A + (size_t)(brow + arow) * K + k0 + ko;
      const uint16_t* gb = W + (size_t)(bcol + arow) * K + k0 + ko;
      GLOAD_LDS16(ga, As + (size_t)(j * 256 + w * 64) * 8);
      GLOAD_LDS16(gb, Bs + (size_t)(j * 256 + w * 64) * 8);
    }
    __syncthreads();

    short8 a[4], b[4];
#pragma unroll
    for (int m = 0; m < 4; ++m) {
      int ar = wr * 64 + m * 16 + l16;
      a[m] = *(const short8*)&As[(ar & 31) * 128 + ((((ar >> 5) * 4 + lhi) ^ (ar & 15))) * 8];
    }
#pragma unroll
    for (int n = 0; n < 4; ++n) {
      int br_ = wc * 64 + n * 16 + l16;
      b[n] = *(const short8*)&Bs[(br_ & 31) * 128 + ((((br_ >> 5) * 4 + lhi) ^ (br_ & 15))) * 8];
    }
#pragma unroll
    for (int m = 0; m < 4; ++m)
#pragma unroll
      for (int n = 0; n < 4; ++n)
        acc[m][n] = MFMA16(a[m], b[n], acc[m][n]);
    __syncthreads();
  }

#pragma unroll
  for (int n = 0; n < 4; ++n) {
    int col = bcol + wc * 64 + n * 16 + l16;
    float bv = bias[col];
    if (MODE == 2) {
      // V output, transposed: 4 j's = 4 consecutive s at fixed (h, d)
      int h = col >> 6, d = col & 63;
#pragma unroll
      for (int m = 0; m < 4; ++m) {
        int row = brow + wr * 64 + m * 16 + lhi * 4;   // j = 0 row
        int b_ = row >> 11, s = row & 2047;
        union { uint16_t u[4]; ushort4v v; } pk4;
#pragma unroll
        for (int j = 0; j < 4; ++j) pk4.u[j] = f2bf(acc[m][n][j] + bv);
        *(ushort4v*)((uint16_t*)Cout + (size_t)(b_ * 16 + h) * 131072 + (size_t)d * 2048 + s) = pk4.v;
      }
    } else {
#pragma unroll
      for (int m = 0; m < 4; ++m) {
#pragma unroll
        for (int j = 0; j < 4; ++j) {
          int row = brow + wr * 64 + m * 16 + lhi * 4 + j;
          float v = (acc[m][n][j] + bv) * scale;
          if (MODE == 1)
            ((uint16_t*)Cout)[(size_t)row * N + col] = f2bf(v);
          else
            ((float*)Cout)[(size_t)row * N + col] = v;
        }
      }
    }
  }
}

// fused Q/K/V projections with XCD-chunked swizzle; V written pre-transposed.
__global__ __launch_bounds__(256)
void gemm_qkv_k(const uint16_t* __restrict__ XQ, const uint16_t* __restrict__ XK,
                const uint16_t* __restrict__ XV, const uint16_t* __restrict__ WQ,
                const uint16_t* __restrict__ WK, const uint16_t* __restrict__ WV,
                const float* __restrict__ bq, const float* __restrict__ bk,
                const float* __restrict__ bv, uint16_t* __restrict__ QP,
                uint16_t* __restrict__ KP, uint16_t* __restrict__ VT, float qscale) {
  const int f = (blockIdx.z * 64 + blockIdx.y) * 8 + blockIdx.x;
  const int virt = (f & 7) * 192 + (f >> 3);
  const int vz = virt >> 9;            // /512
  const int vy = (virt & 511) >> 3;
  const int vx = virt & 7;

  if (vz == 0)      gemm_body<1>(XQ, WQ, bq, QP, qscale, vy * 128, vx * 128);
  else if (vz == 1) gemm_body<1>(XK, WK, bk, KP, 1.0f,  vy * 128, vx * 128);
  else              gemm_body<2>(XV, WV, bv, VT, 1.0f,  vy * 128, vx * 128);
}

// output projection, 512 blocks: virt = (f&7)*64 + f>>3 -> 8 y-groups per XCD.
__global__ __launch_bounds__(256)
void gemm_o_k(const uint16_t* __restrict__ A, const uint16_t* __restrict__ W,
              const float* __restrict__ bias, float* __restrict__ Cout) {
  const int f = blockIdx.y * 8 + blockIdx.x;
  const int virt = (f & 7) * 64 + (f >> 3);
  const int vy = virt >> 3;
  const int vx = virt & 7;
  gemm_body<0>(A, W, bias, Cout, 1.0f, vy * 128, vx * 128);
}

// ---------- flash attention: quarter-pipelined (QK_next ∥ exp/pack_cur) ----------
__global__ __launch_bounds__(512, 2)
void attn_k(const uint16_t* __restrict__ Qp, const uint16_t* __restrict__ Kp,
            const uint16_t* __restrict__ Vt, uint16_t* __restrict__ AO) {
  __shared__ uint16_t Kl[2][64 * 128];   // 16KB per buffer
  __shared__ uint16_t Vl[2][64 * 128];   // 16KB per buffer

  const int t = threadIdx.x;
  const int l = t & 63, w = t >> 6;       // w = 0..7
  const int l32 = l & 31, hi = l >> 5;

  // XCD-chunked swizzle: 512 blocks, 64 per XCD -> 8 contiguous bh groups each.
  const int f = blockIdx.y * 8 + blockIdx.x;
  const int virt = (f & 7) * 64 + (f >> 3);
  const int vx = virt & 7;     // q-block (256 q each)
  const int vy = virt >> 3;    // bh

  const int q0 = vx * 256 + w * 32;
  const size_t base = (size_t)(vy >> 4) * 2048 * 1024 + (size_t)(vy & 15) * 64;
  const size_t vbg = (size_t)vy * 131072;  // (b*16+h)*64*2048

  union PAu { uint32_t u[4]; short8 s; };

  // staging: 1024 chunks per matrix per tile; 512 threads -> 2 issues each.
  const uint16_t* pK[2];
  const uint16_t* pV[2];
#pragma unroll
  for (int i = 0; i < 2; ++i) {
    int c = i * 512 + t;
    int r = c >> 4, qs = c & 15;
    int q0c = qs ^ (r & 15);
    pK[i] = Kp + base + (size_t)(64 * (q0c >> 3) + r) * 1024 + (q0c & 7) * 8;
    pV[i] = Vt + vbg + (size_t)r * 2048 + q0c * 8;
  }

#define STAGE_ALL(NB)                                                 \
  {                                                                   \
    _Pragma("unroll") for (int i = 0; i < 2; ++i) {                   \
      GLOAD_LDS16(pK[i], &Kl[NB][(size_t)(i * 512 + w * 64) * 8]);    \
      GLOAD_LDS16(pV[i], &Vl[NB][(size_t)(i * 512 + w * 64) * 8]);    \
      pK[i] += 131072;  /* +128 source rows */                        \
      pV[i] += 128;     /* +128 s columns  */                        \
    }                                                                 \
  }

  // Q B-frags: lane holds Q[q0 + l32][k = ks*16 + hi*8 + i]
  short8 qf[4];
#pragma unroll
  for (int ks = 0; ks < 4; ++ks)
    qf[ks] = *(const short8*)(Qp + base + (size_t)(q0 + l32) * 1024 + ks * 16 + hi * 8);

  floatx16 of0 = {}, of1 = {};   // O[q][d] C-frags
  float rs = 0.f;                // per-lane partial rowsum

  const int swzb = (l32 & 15);
  const int krow = l32 * 256;    // byte base of LDS row l32 (row +32 = +8192)

  STAGE_ALL(0);
  __syncthreads();

#define QK_Q(SF, CUR, H, RH)                                                          \
  {                                                                                   \
    _Pragma("unroll") for (int ks = 0; ks < 4; ++ks) {                                \
      int kbyte = krow + (RH) * 8192 + ((((H) * 8 + 2 * ks + hi) ^ swzb) << 4);       \
      short8 kf = *(const short8*)((char*)Kl[CUR] + kbyte);                           \
      SF = MFMA32(kf, qf[ks], SF);                                                    \
    }                                                                                 \
  }

#define EXPPACK(SF, P0, P1)                                                           \
  {                                                                                   \
    _Pragma("unroll") for (int r = 0; r < 16; ++r) {                                  \
      SF[r] = __builtin_amdgcn_exp2f(SF[r]);                                          \
      rs += SF[r];                                                                    \
    }                                                                                 \
    uint32_t a0, a1, b0, b1;                                                          \
    CVTPK(SF[0], SF[1], a0); CVTPK(SF[2], SF[3], a1);                                 \
    CVTPK(SF[4], SF[5], b0); CVTPK(SF[6], SF[7], b1);                                 \
    SWAP32(a0, b0); SWAP32(a1, b1);                                                   \
    P0.u[0] = a0; P0.u[1] = a1; P0.u[2] = b0; P0.u[3] = b1;                           \
    CVTPK(SF[8], SF[9], a0); CVTPK(SF[10], SF[11], a1);                               \
    CVTPK(SF[12], SF[13], b0); CVTPK(SF[14], SF[15], b1);                             \
    SWAP32(a0, b0); SWAP32(a1, b1);                                                   \
    P1.u[0] = a0; P1.u[1] = a1; P1.u[2] = b0; P1.u[3] = b1;                           \
  }

#define PV_Q(P0, P1, CUR, H, RH)                                                      \
  {                                                                                   \
    int vb0 = krow + ((((H) * 8 + 2 * (2 * (RH)) + hi) ^ swzb) << 4);                 \
    int vb1 = krow + ((((H) * 8 + 2 * (2 * (RH) + 1) + hi) ^ swzb) << 4);             \
    short8 vf00 = *(const short8*)((char*)Vl[CUR] + vb0);                             \
    short8 vf01 = *(const short8*)((char*)Vl[CUR] + vb0 + 8192);                      \
    short8 vf10 = *(const short8*)((char*)Vl[CUR] + vb1);                             \
    short8 vf11 = *(const short8*)((char*)Vl[CUR] + vb1 + 8192);                      \
    of0 = MFMA32(P0.s, vf00, of0);                                                    \
    of1 = MFMA32(P0.s, vf01, of1);                                                    \
    of0 = MFMA32(P1.s, vf10, of0);                                                    \
    of1 = MFMA32(P1.s, vf11, of1);                                                    \
  }

#define STEP128(CUR, PF)                                                              \
  {                                                                                   \
    if (PF) STAGE_ALL(CUR ^ 1);                                                       \
    floatx16 sfA = {}, sfB = {};                                                      \
    QK_Q(sfA, CUR, 0, 0);                                                             \
    QK_Q(sfB, CUR, 0, 1);                                                             \
    {                                                                                 \
      PAu p0, p1;                                                                     \
      EXPPACK(sfA, p0, p1);                                                           \
      PV_Q(p0, p1, CUR, 0, 0);                                                        \
    }                                                                                 \
    sfA = (floatx16){};                                                               \
    QK_Q(sfA, CUR, 1, 0);                                                             \
    {                                                                                 \
      PAu p0, p1;                                                                     \
      EXPPACK(sfB, p0, p1);                                                           \
      PV_Q(p0, p1, CUR, 0, 1);                                                        \
    }                                                                                 \
    sfB = (floatx16){};                                                               \
    QK_Q(sfB, CUR, 1, 1);                                                             \
    {                                                                                 \
      PAu p0, p1;                                                                     \
      EXPPACK(sfA, p0, p1);                                                           \
      PV_Q(p0, p1, CUR, 1, 0);                                                        \
    }                                                                                 \
    {                                                                                 \
      PAu p0, p1;                                                                     \
      EXPPACK(sfB, p0, p1);                                                           \
      PV_Q(p0, p1, CUR, 1, 1);                                                        \
    }                                                                                 \
    __syncthreads();                                                                  \
  }

  for (int it = 0; it < 8; ++it) {   // 16 kv-tiles of 128, 2 per iteration
    STEP128(0, 1);
    STEP128(1, it < 7);
  }

  // --- epilogue: complete rowsums and normalize.
  rs += __shfl_xor(rs, 32);          // full rowsum for q = l32 (both hi halves)
#pragma unroll
  for (int r = 0; r < 16; ++r) {
    int qloc = (r & 3) + 8 * (r >> 2) + 4 * hi;       // q index of of-frag row r
    float rsq = __shfl(rs, qloc);                      // rowsum for that q
    float rinv = 1.0f / rsq;
    int qrow = q0 + qloc;
    AO[base + (size_t)qrow * 1024 + l32]      = f2bf(of0[r] * rinv);
    AO[base + (size_t)qrow * 1024 + 32 + l32] = f2bf(of1[r] * rinv);
  }
#undef STAGE_ALL
#undef QK_Q
#undef EXPPACK
#undef PV_Q
#undef STEP128
}

// ---------- launch ----------
extern "C" void kernel_launch(void* const* d_in, const int* in_sizes, int n_in,
                              void* d_out, int out_size, void* d_ws, size_t ws_size,
                              hipStream_t stream) {
  const float* q  = (const float*)d_in[0];
  const float* k  = (const float*)d_in[1];
  const float* v  = (const float*)d_in[2];
  const float* Wq = (const float*)d_in[3];
  const float* bq = (const float*)d_in[4];
  const float* Wk = (const float*)d_in[5];
  const float* bk = (const float*)d_in[6];
  const float* Wv = (const float*)d_in[7];
  const float* bv = (const float*)d_in[8];
  const float* Wo = (const float*)d_in[9];
  const float* bo = (const float*)d_in[10];

  const size_t MB = 1ull << 20;
  char* ws = (char*)d_ws;
  uint16_t* XQ  = (uint16_t*)(ws + 0 * MB);    // 16MB x3, contiguous (cvt3 strides)
  uint16_t* XK  = (uint16_t*)(ws + 16 * MB);
  uint16_t* XV  = (uint16_t*)(ws + 32 * MB);
  uint16_t* WQb = (uint16_t*)(ws + 48 * MB);   // 2MB x4, contiguous (cvt4 strides)
  uint16_t* WKb = (uint16_t*)(ws + 50 * MB);
  uint16_t* WVb = (uint16_t*)(ws + 52 * MB);
  uint16_t* WOb = (uint16_t*)(ws + 54 * MB);
  uint16_t* QP  = (uint16_t*)(ws + 56 * MB);
  uint16_t* KP  = (uint16_t*)(ws + 72 * MB);
  uint16_t* VT  = (uint16_t*)(ws + 88 * MB);   // V projected + transposed, 16MB
  uint16_t* AO  = XQ;   // alias: XQ dead after QKV projection

  const int NTOK = 4 * 2048;
  const int D = 1024;
  const int nBig = NTOK * D / 4;  // 2M float4
  const int nW = D * D / 4;       // 256K float4
  const float qscale = 0.125f * 1.4426950408889634f;  // softmax scale * log2e -> exp2

  cvt3_k<<<dim3(2048, 1, 3), dim3(256), 0, stream>>>(q, k, v, XQ, nBig);
  cvt4_k<<<dim3(1024, 1, 4), dim3(256), 0, stream>>>(Wq, Wk, Wv, Wo, WQb, nW);

  gemm_qkv_k<<<dim3(D / 128, NTOK / 128, 3), dim3(256), 0, stream>>>(
      XQ, XK, XV, WQb, WKb, WVb, bq, bk, bv, QP, KP, VT, qscale);

  attn_k<<<dim3(8, 64), dim3(512), 0, stream>>>(QP, KP, VT, AO);

  gemm_o_k<<<dim3(D / 128, NTOK / 128), dim3(256), 0, stream>>>(AO, WOb, bo, (float*)d_out);
}

// Round 13
// 196.393 us; speedup vs baseline: 1.1058x; 1.0014x over previous
//
#include <hip/hip_runtime.h>
#include <hip/hip_bf16.h>
#include <stdint.h>

// ---------- types ----------
typedef __attribute__((ext_vector_type(8))) short short8;      // 8 bf16 (MFMA A/B frag)
typedef __attribute__((ext_vector_type(4))) float floatx4;     // 16x16 C/D frag
typedef __attribute__((ext_vector_type(16))) float floatx16;   // 32x32 C/D frag
typedef __attribute__((ext_vector_type(4))) uint16_t ushort4v;

#define MFMA16(a, b, c) __builtin_amdgcn_mfma_f32_16x16x32_bf16((a), (b), (c), 0, 0, 0)
#define MFMA32(a, b, c) __builtin_amdgcn_mfma_f32_32x32x16_bf16((a), (b), (c), 0, 0, 0)

// async global->LDS, 16B per lane; LDS dest is wave-uniform base + lane*16
#define GLOAD_LDS16(g, l)                                                          \
  __builtin_amdgcn_global_load_lds(                                                \
      (const __attribute__((address_space(1))) uint32_t*)(g),                      \
      (__attribute__((address_space(3))) uint32_t*)(l), 16, 0, 0)

// packed f32x2 -> bf16x2
#define CVTPK(lo_, hi_, out_) \
  asm("v_cvt_pk_bf16_f32 %0, %1, %2" : "=v"(out_) : "v"(lo_), "v"(hi_))
// exchange a's high 32 lanes with b's low 32 lanes
#define SWAP32(a_, b_) \
  asm("v_permlane32_swap_b32 %0, %1" : "+v"(a_), "+v"(b_))

// fp32 -> bf16 round-to-nearest-even
__device__ __forceinline__ uint16_t f2bf(float x) {
  union { float f; uint32_t u; } c; c.f = x;
  return (uint16_t)((c.u + 0x7FFFu + ((c.u >> 16) & 1u)) >> 16);
}

// ---------- fp32 -> bf16 converts, z-batched ----------
__global__ void cvt3_k(const float* __restrict__ s0, const float* __restrict__ s1,
                       const float* __restrict__ s2, uint16_t* __restrict__ dst, int n4) {
  const float* src = blockIdx.z == 0 ? s0 : (blockIdx.z == 1 ? s1 : s2);
  uint16_t* d = dst + (size_t)blockIdx.z * 8388608;  // 16MB stride
  int stride = gridDim.x * blockDim.x;
  for (int i = blockIdx.x * blockDim.x + threadIdx.x; i < n4; i += stride) {
    float4 v = ((const float4*)src)[i];
    ushort4v o;
    o.x = f2bf(v.x); o.y = f2bf(v.y); o.z = f2bf(v.z); o.w = f2bf(v.w);
    ((ushort4v*)d)[i] = o;
  }
}
__global__ void cvt4_k(const float* __restrict__ s0, const float* __restrict__ s1,
                       const float* __restrict__ s2, const float* __restrict__ s3,
                       uint16_t* __restrict__ dst, int n4) {
  const float* src = blockIdx.z == 0 ? s0 : (blockIdx.z == 1 ? s1 : (blockIdx.z == 2 ? s2 : s3));
  uint16_t* d = dst + (size_t)blockIdx.z * 1048576;  // 2MB stride
  int stride = gridDim.x * blockDim.x;
  for (int i = blockIdx.x * blockDim.x + threadIdx.x; i < n4; i += stride) {
    float4 v = ((const float4*)src)[i];
    ushort4v o;
    o.x = f2bf(v.x); o.y = f2bf(v.y); o.z = f2bf(v.z); o.w = f2bf(v.w);
    ((ushort4v*)d)[i] = o;
  }
}

// ---------- GEMM body: C[8192,1024] = (A @ W^T + bias) * scale ----------
// MODE: 0 = f32 row-major out, 1 = bf16 row-major out, 2 = bf16 V-transposed out
// (VT[(b*16+h)*64+d][s], packed 4-wide along s).
// LDS tiles: [32 rows][16 slots of 16B], slot q of row r holds chunk q^(r&15)
// (chunk c: arow = 32*(q0>>2) + r, kchunk = q0&3) -> frag reads conflict-free.
template <int MODE>
__device__ __forceinline__ void gemm_body(const uint16_t* __restrict__ A,
                                          const uint16_t* __restrict__ W,
                                          const float* __restrict__ bias,
                                          void* __restrict__ Cout, float scale,
                                          int brow, int bcol) {
  constexpr int N = 1024, K = 1024;
  __shared__ uint16_t As[32 * 128];   // 8KB, 256B rows
  __shared__ uint16_t Bs[32 * 128];
  const int t = threadIdx.x;
  const int l = t & 63;
  const int w = t >> 6;
  const int wr = w >> 1, wc = w & 1;
  const int l16 = l & 15, lhi = l >> 4;

  floatx4 acc[4][4] = {};

  for (int k0 = 0; k0 < K; k0 += 32) {
#pragma unroll
    for (int j = 0; j < 2; ++j) {
      int c = j * 256 + t;
      int r = c >> 4, qs = c & 15;
      int q0 = qs ^ (r & 15);
      int arow = 32 * (q0 >> 2) + r;
      int ko = (q0 & 3) * 8;
      const uint16_t* ga = A + (size_t)(brow + arow) * K + k0 + ko;
      const uint16_t* gb = W + (size_t)(bcol + arow) * K + k0 + ko;
      GLOAD_LDS16(ga, As + (size_t)(j * 256 + w * 64) * 8);
      GLOAD_LDS16(gb, Bs + (size_t)(j * 256 + w * 64) * 8);
    }
    __syncthreads();

    short8 a[4], b[4];
#pragma unroll
    for (int m = 0; m < 4; ++m) {
      int ar = wr * 64 + m * 16 + l16;
      a[m] = *(const short8*)&As[(ar & 31) * 128 + ((((ar >> 5) * 4 + lhi) ^ (ar & 15))) * 8];
    }
#pragma unroll
    for (int n = 0; n < 4; ++n) {
      int br_ = wc * 64 + n * 16 + l16;
      b[n] = *(const short8*)&Bs[(br_ & 31) * 128 + ((((br_ >> 5) * 4 + lhi) ^ (br_ & 15))) * 8];
    }
#pragma unroll
    for (int m = 0; m < 4; ++m)
#pragma unroll
      for (int n = 0; n < 4; ++n)
        acc[m][n] = MFMA16(a[m], b[n], acc[m][n]);
    __syncthreads();
  }

#pragma unroll
  for (int n = 0; n < 4; ++n) {
    int col = bcol + wc * 64 + n * 16 + l16;
    float bv = bias[col];
    if (MODE == 2) {
      // V output, transposed: 4 j's = 4 consecutive s at fixed (h, d)
      int h = col >> 6, d = col & 63;
#pragma unroll
      for (int m = 0; m < 4; ++m) {
        int row = brow + wr * 64 + m * 16 + lhi * 4;   // j = 0 row
        int b_ = row >> 11, s = row & 2047;
        union { uint16_t u[4]; ushort4v v; } pk4;
#pragma unroll
        for (int j = 0; j < 4; ++j) pk4.u[j] = f2bf(acc[m][n][j] + bv);
        *(ushort4v*)((uint16_t*)Cout + (size_t)(b_ * 16 + h) * 131072 + (size_t)d * 2048 + s) = pk4.v;
      }
    } else {
#pragma unroll
      for (int m = 0; m < 4; ++m) {
#pragma unroll
        for (int j = 0; j < 4; ++j) {
          int row = brow + wr * 64 + m * 16 + lhi * 4 + j;
          float v = (acc[m][n][j] + bv) * scale;
          if (MODE == 1)
            ((uint16_t*)Cout)[(size_t)row * N + col] = f2bf(v);
          else
            ((float*)Cout)[(size_t)row * N + col] = v;
        }
      }
    }
  }
}

// fused Q/K/V projections with XCD-chunked swizzle; V written pre-transposed.
__global__ __launch_bounds__(256)
void gemm_qkv_k(const uint16_t* __restrict__ XQ, const uint16_t* __restrict__ XK,
                const uint16_t* __restrict__ XV, const uint16_t* __restrict__ WQ,
                const uint16_t* __restrict__ WK, const uint16_t* __restrict__ WV,
                const float* __restrict__ bq, const float* __restrict__ bk,
                const float* __restrict__ bv, uint16_t* __restrict__ QP,
                uint16_t* __restrict__ KP, uint16_t* __restrict__ VT, float qscale) {
  const int f = (blockIdx.z * 64 + blockIdx.y) * 8 + blockIdx.x;
  const int virt = (f & 7) * 192 + (f >> 3);
  const int vz = virt >> 9;            // /512
  const int vy = (virt & 511) >> 3;
  const int vx = virt & 7;

  if (vz == 0)      gemm_body<1>(XQ, WQ, bq, QP, qscale, vy * 128, vx * 128);
  else if (vz == 1) gemm_body<1>(XK, WK, bk, KP, 1.0f,  vy * 128, vx * 128);
  else              gemm_body<2>(XV, WV, bv, VT, 1.0f,  vy * 128, vx * 128);
}

// output projection, 512 blocks: virt = (f&7)*64 + f>>3 -> 8 y-groups per XCD.
__global__ __launch_bounds__(256)
void gemm_o_k(const uint16_t* __restrict__ A, const uint16_t* __restrict__ W,
              const float* __restrict__ bias, float* __restrict__ Cout) {
  const int f = blockIdx.y * 8 + blockIdx.x;
  const int virt = (f & 7) * 64 + (f >> 3);
  const int vy = virt >> 3;
  const int vx = virt & 7;
  gemm_body<0>(A, W, bias, Cout, 1.0f, vy * 128, vx * 128);
}

// ---------- flash attention: quarter-pipelined (QK_next ∥ exp/pack_cur) ----------
__global__ __launch_bounds__(512, 2)
void attn_k(const uint16_t* __restrict__ Qp, const uint16_t* __restrict__ Kp,
            const uint16_t* __restrict__ Vt, uint16_t* __restrict__ AO) {
  __shared__ uint16_t Kl[2][64 * 128];   // 16KB per buffer
  __shared__ uint16_t Vl[2][64 * 128];   // 16KB per buffer

  const int t = threadIdx.x;
  const int l = t & 63, w = t >> 6;       // w = 0..7
  const int l32 = l & 31, hi = l >> 5;

  // XCD-chunked swizzle: 512 blocks, 64 per XCD -> 8 contiguous bh groups each.
  const int f = blockIdx.y * 8 + blockIdx.x;
  const int virt = (f & 7) * 64 + (f >> 3);
  const int vx = virt & 7;     // q-block (256 q each)
  const int vy = virt >> 3;    // bh

  const int q0 = vx * 256 + w * 32;
  const size_t base = (size_t)(vy >> 4) * 2048 * 1024 + (size_t)(vy & 15) * 64;
  const size_t vbg = (size_t)vy * 131072;  // (b*16+h)*64*2048

  union PAu { uint32_t u[4]; short8 s; };

  // staging: 1024 chunks per matrix per tile; 512 threads -> 2 issues each.
  const uint16_t* pK[2];
  const uint16_t* pV[2];
#pragma unroll
  for (int i = 0; i < 2; ++i) {
    int c = i * 512 + t;
    int r = c >> 4, qs = c & 15;
    int q0c = qs ^ (r & 15);
    pK[i] = Kp + base + (size_t)(64 * (q0c >> 3) + r) * 1024 + (q0c & 7) * 8;
    pV[i] = Vt + vbg + (size_t)r * 2048 + q0c * 8;
  }

#define STAGE_ALL(NB)                                                 \
  {                                                                   \
    _Pragma("unroll") for (int i = 0; i < 2; ++i) {                   \
      GLOAD_LDS16(pK[i], &Kl[NB][(size_t)(i * 512 + w * 64) * 8]);    \
      GLOAD_LDS16(pV[i], &Vl[NB][(size_t)(i * 512 + w * 64) * 8]);    \
      pK[i] += 131072;  /* +128 source rows */                        \
      pV[i] += 128;     /* +128 s columns  */                        \
    }                                                                 \
  }

  // Q B-frags: lane holds Q[q0 + l32][k = ks*16 + hi*8 + i]
  short8 qf[4];
#pragma unroll
  for (int ks = 0; ks < 4; ++ks)
    qf[ks] = *(const short8*)(Qp + base + (size_t)(q0 + l32) * 1024 + ks * 16 + hi * 8);

  floatx16 of0 = {}, of1 = {};   // O[q][d] C-frags
  float rs = 0.f;                // per-lane partial rowsum

  const int swzb = (l32 & 15);
  const int krow = l32 * 256;    // byte base of LDS row l32 (row +32 = +8192)

  STAGE_ALL(0);
  __syncthreads();

#define QK_Q(SF, CUR, H, RH)                                                          \
  {                                                                                   \
    _Pragma("unroll") for (int ks = 0; ks < 4; ++ks) {                                \
      int kbyte = krow + (RH) * 8192 + ((((H) * 8 + 2 * ks + hi) ^ swzb) << 4);       \
      short8 kf = *(const short8*)((char*)Kl[CUR] + kbyte);                           \
      SF = MFMA32(kf, qf[ks], SF);                                                    \
    }                                                                                 \
  }

#define EXPPACK(SF, P0, P1)                                                           \
  {                                                                                   \
    _Pragma("unroll") for (int r = 0; r < 16; ++r) {                                  \
      SF[r] = __builtin_amdgcn_exp2f(SF[r]);                                          \
      rs += SF[r];                                                                    \
    }                                                                                 \
    uint32_t a0, a1, b0, b1;                                                          \
    CVTPK(SF[0], SF[1], a0); CVTPK(SF[2], SF[3], a1);                                 \
    CVTPK(SF[4], SF[5], b0); CVTPK(SF[6], SF[7], b1);                                 \
    SWAP32(a0, b0); SWAP32(a1, b1);                                                   \
    P0.u[0] = a0; P0.u[1] = a1; P0.u[2] = b0; P0.u[3] = b1;                           \
    CVTPK(SF[8], SF[9], a0); CVTPK(SF[10], SF[11], a1);                               \
    CVTPK(SF[12], SF[13], b0); CVTPK(SF[14], SF[15], b1);                             \
    SWAP32(a0, b0); SWAP32(a1, b1);                                                   \
    P1.u[0] = a0; P1.u[1] = a1; P1.u[2] = b0; P1.u[3] = b1;                           \
  }

#define PV_Q(P0, P1, CUR, H, RH)                                                      \
  {                                                                                   \
    int vb0 = krow + ((((H) * 8 + 2 * (2 * (RH)) + hi) ^ swzb) << 4);                 \
    int vb1 = krow + ((((H) * 8 + 2 * (2 * (RH) + 1) + hi) ^ swzb) << 4);             \
    short8 vf00 = *(const short8*)((char*)Vl[CUR] + vb0);                             \
    short8 vf01 = *(const short8*)((char*)Vl[CUR] + vb0 + 8192);                      \
    short8 vf10 = *(const short8*)((char*)Vl[CUR] + vb1);                             \
    short8 vf11 = *(const short8*)((char*)Vl[CUR] + vb1 + 8192);                      \
    of0 = MFMA32(P0.s, vf00, of0);                                                    \
    of1 = MFMA32(P0.s, vf01, of1);                                                    \
    of0 = MFMA32(P1.s, vf10, of0);                                                    \
    of1 = MFMA32(P1.s, vf11, of1);                                                    \
  }

#define STEP128(CUR, PF)                                                              \
  {                                                                                   \
    if (PF) STAGE_ALL(CUR ^ 1);                                                       \
    floatx16 sfA = {}, sfB = {};                                                      \
    QK_Q(sfA, CUR, 0, 0);                                                             \
    QK_Q(sfB, CUR, 0, 1);                                                             \
    {                                                                                 \
      PAu p0, p1;                                                                     \
      EXPPACK(sfA, p0, p1);                                                           \
      PV_Q(p0, p1, CUR, 0, 0);                                                        \
    }                                                                                 \
    sfA = (floatx16){};                                                               \
    QK_Q(sfA, CUR, 1, 0);                                                             \
    {                                                                                 \
      PAu p0, p1;                                                                     \
      EXPPACK(sfB, p0, p1);                                                           \
      PV_Q(p0, p1, CUR, 0, 1);                                                        \
    }                                                                                 \
    sfB = (floatx16){};                                                               \
    QK_Q(sfB, CUR, 1, 1);                                                             \
    {                                                                                 \
      PAu p0, p1;                                                                     \
      EXPPACK(sfA, p0, p1);                                                           \
      PV_Q(p0, p1, CUR, 1, 0);                                                        \
    }                                                                                 \
    {                                                                                 \
      PAu p0, p1;                                                                     \
      EXPPACK(sfB, p0, p1);                                                           \
      PV_Q(p0, p1, CUR, 1, 1);                                                        \
    }                                                                                 \
    __syncthreads();                                                                  \
  }

  for (int it = 0; it < 8; ++it) {   // 16 kv-tiles of 128, 2 per iteration
    STEP128(0, 1);
    STEP128(1, it < 7);
  }

  // --- epilogue: complete rowsums and normalize.
  rs += __shfl_xor(rs, 32);          // full rowsum for q = l32 (both hi halves)
#pragma unroll
  for (int r = 0; r < 16; ++r) {
    int qloc = (r & 3) + 8 * (r >> 2) + 4 * hi;       // q index of of-frag row r
    float rsq = __shfl(rs, qloc);                      // rowsum for that q
    float rinv = 1.0f / rsq;
    int qrow = q0 + qloc;
    AO[base + (size_t)qrow * 1024 + l32]      = f2bf(of0[r] * rinv);
    AO[base + (size_t)qrow * 1024 + 32 + l32] = f2bf(of1[r] * rinv);
  }
#undef STAGE_ALL
#undef QK_Q
#undef EXPPACK
#undef PV_Q
#undef STEP128
}

// ---------- launch ----------
extern "C" void kernel_launch(void* const* d_in, const int* in_sizes, int n_in,
                              void* d_out, int out_size, void* d_ws, size_t ws_size,
                              hipStream_t stream) {
  const float* q  = (const float*)d_in[0];
  const float* k  = (const float*)d_in[1];
  const float* v  = (const float*)d_in[2];
  const float* Wq = (const float*)d_in[3];
  const float* bq = (const float*)d_in[4];
  const float* Wk = (const float*)d_in[5];
  const float* bk = (const float*)d_in[6];
  const float* Wv = (const float*)d_in[7];
  const float* bv = (const float*)d_in[8];
  const float* Wo = (const float*)d_in[9];
  const float* bo = (const float*)d_in[10];

  const size_t MB = 1ull << 20;
  char* ws = (char*)d_ws;
  uint16_t* XQ  = (uint16_t*)(ws + 0 * MB);    // 16MB x3, contiguous (cvt3 strides)
  uint16_t* XK  = (uint16_t*)(ws + 16 * MB);
  uint16_t* XV  = (uint16_t*)(ws + 32 * MB);
  uint16_t* WQb = (uint16_t*)(ws + 48 * MB);   // 2MB x4, contiguous (cvt4 strides)
  uint16_t* WKb = (uint16_t*)(ws + 50 * MB);
  uint16_t* WVb = (uint16_t*)(ws + 52 * MB);
  uint16_t* WOb = (uint16_t*)(ws + 54 * MB);
  uint16_t* QP  = (uint16_t*)(ws + 56 * MB);
  uint16_t* KP  = (uint16_t*)(ws + 72 * MB);
  uint16_t* VT  = (uint16_t*)(ws + 88 * MB);   // V projected + transposed, 16MB
  uint16_t* AO  = XQ;   // alias: XQ dead after QKV projection

  const int NTOK = 4 * 2048;
  const int D = 1024;
  const int nBig = NTOK * D / 4;  // 2M float4
  const int nW = D * D / 4;       // 256K float4
  const float qscale = 0.125f * 1.4426950408889634f;  // softmax scale * log2e -> exp2

  cvt3_k<<<dim3(2048, 1, 3), dim3(256), 0, stream>>>(q, k, v, XQ, nBig);
  cvt4_k<<<dim3(1024, 1, 4), dim3(256), 0, stream>>>(Wq, Wk, Wv, Wo, WQb, nW);

  gemm_qkv_k<<<dim3(D / 128, NTOK / 128, 3), dim3(256), 0, stream>>>(
      XQ, XK, XV, WQb, WKb, WVb, bq, bk, bv, QP, KP, VT, qscale);

  attn_k<<<dim3(8, 64), dim3(512), 0, stream>>>(QP, KP, VT, AO);

  gemm_o_k<<<dim3(D / 128, NTOK / 128), dim3(256), 0, stream>>>(AO, WOb, bo, (float*)d_out);
}

// Round 15
// 185.668 us; speedup vs baseline: 1.1697x; 1.0578x over previous
//
#include <hip/hip_runtime.h>
#include <hip/hip_bf16.h>
#include <stdint.h>

// ---------- types ----------
typedef __attribute__((ext_vector_type(8))) short short8;      // 8 bf16 (MFMA A/B frag)
typedef __attribute__((ext_vector_type(4))) float floatx4;     // 16x16 C/D frag
typedef __attribute__((ext_vector_type(16))) float floatx16;   // 32x32 C/D frag
typedef __attribute__((ext_vector_type(4))) uint16_t ushort4v;

#define MFMA16(a, b, c) __builtin_amdgcn_mfma_f32_16x16x32_bf16((a), (b), (c), 0, 0, 0)
#define MFMA32(a, b, c) __builtin_amdgcn_mfma_f32_32x32x16_bf16((a), (b), (c), 0, 0, 0)

// async global->LDS, 16B per lane; LDS dest is wave-uniform base + lane*16
#define GLOAD_LDS16(g, l)                                                          \
  __builtin_amdgcn_global_load_lds(                                                \
      (const __attribute__((address_space(1))) uint32_t*)(g),                      \
      (__attribute__((address_space(3))) uint32_t*)(l), 16, 0, 0)

// packed f32x2 -> bf16x2
#define CVTPK(lo_, hi_, out_) \
  asm("v_cvt_pk_bf16_f32 %0, %1, %2" : "=v"(out_) : "v"(lo_), "v"(hi_))
// exchange a's high 32 lanes with b's low 32 lanes
#define SWAP32(a_, b_) \
  asm("v_permlane32_swap_b32 %0, %1" : "+v"(a_), "+v"(b_))

#define WAITVM(N)                                          \
  {                                                        \
    asm volatile("s_waitcnt vmcnt(" #N ")" ::: "memory");  \
    __builtin_amdgcn_sched_barrier(0);                     \
  }
#define SBAR                                               \
  {                                                        \
    __builtin_amdgcn_s_barrier();                          \
    __builtin_amdgcn_sched_barrier(0);                     \
  }

// fp32 -> bf16 round-to-nearest-even
__device__ __forceinline__ uint16_t f2bf(float x) {
  union { float f; uint32_t u; } c; c.f = x;
  return (uint16_t)((c.u + 0x7FFFu + ((c.u >> 16) & 1u)) >> 16);
}

// ---------- fp32 -> bf16 converts, z-batched ----------
__global__ void cvt3_k(const float* __restrict__ s0, const float* __restrict__ s1,
                       const float* __restrict__ s2, uint16_t* __restrict__ dst, int n4) {
  const float* src = blockIdx.z == 0 ? s0 : (blockIdx.z == 1 ? s1 : s2);
  uint16_t* d = dst + (size_t)blockIdx.z * 8388608;  // 16MB stride
  int stride = gridDim.x * blockDim.x;
  for (int i = blockIdx.x * blockDim.x + threadIdx.x; i < n4; i += stride) {
    float4 v = ((const float4*)src)[i];
    ushort4v o;
    o.x = f2bf(v.x); o.y = f2bf(v.y); o.z = f2bf(v.z); o.w = f2bf(v.w);
    ((ushort4v*)d)[i] = o;
  }
}
__global__ void cvt4_k(const float* __restrict__ s0, const float* __restrict__ s1,
                       const float* __restrict__ s2, const float* __restrict__ s3,
                       uint16_t* __restrict__ dst, int n4) {
  const float* src = blockIdx.z == 0 ? s0 : (blockIdx.z == 1 ? s1 : (blockIdx.z == 2 ? s2 : s3));
  uint16_t* d = dst + (size_t)blockIdx.z * 1048576;  // 2MB stride
  int stride = gridDim.x * blockDim.x;
  for (int i = blockIdx.x * blockDim.x + threadIdx.x; i < n4; i += stride) {
    float4 v = ((const float4*)src)[i];
    ushort4v o;
    o.x = f2bf(v.x); o.y = f2bf(v.y); o.z = f2bf(v.z); o.w = f2bf(v.w);
    ((ushort4v*)d)[i] = o;
  }
}

// ---------- GEMM: 256x128 tile, BK=64, 8 waves, 3-buffer counted-vmcnt pipeline ----
// LDS is declared in the CALLER kernel (single allocation) and passed in —
// declaring it here duplicated 144KB per template instantiation (R13 compile fail).
// Per K-tile kt: stage kt+2 -> buf[(kt+2)%3] (6 gload_lds), compute buf[kt%3],
// s_waitcnt vmcnt(6) (kt+1's 6 loads are the oldest; fresh loads stay in flight),
// raw s_barrier (no vmcnt(0) drain). 3-buf rotation: buf p re-staged only by loads
// issued one full K-tile after its last read finished behind a barrier.
// LDS half-unit (proven R6/R11 pattern): [64 r][16 slots x 16B]; slot q of row r
// holds q0 = q^(r&15): source row 64*(q0>>3)+r, kchunk q0&7.
// MODE: 0 = f32 out, 1 = bf16 out, 2 = bf16 V-transposed out.
template <int MODE>
__device__ __forceinline__ void gemm256_body(uint16_t* __restrict__ As,   // LDS, 3*16384
                                             uint16_t* __restrict__ Bs,   // LDS, 3*8192
                                             const uint16_t* __restrict__ A,
                                             const uint16_t* __restrict__ W,
                                             const float* __restrict__ bias,
                                             void* __restrict__ Cout, float scale,
                                             int brow, int bcol) {
  constexpr int N = 1024, K = 1024;
  const int t = threadIdx.x;
  const int l = t & 63, w = t >> 6;       // 8 waves
  const int l16 = l & 15, lhi = (l >> 4) & 3;
  const int wm = w >> 1, wn = w & 1;      // 4 M-waves x 2 N-waves; per-wave C 64x64

  // staging source pointers (advance +64 per K-tile)
  const uint16_t* pA[4];
  const uint16_t* pB[2];
#pragma unroll
  for (int i = 0; i < 4; ++i) {
    int cw = (i * 512 + t) & 1023;
    int r = cw >> 4, q = cw & 15;
    int q0 = q ^ (r & 15);
    pA[i] = A + (size_t)(brow + (i >> 1) * 128 + 64 * (q0 >> 3) + r) * K + (q0 & 7) * 8;
  }
#pragma unroll
  for (int i = 0; i < 2; ++i) {
    int c = i * 512 + t;
    int r = c >> 4, q = c & 15;
    int q0 = q ^ (r & 15);
    pB[i] = W + (size_t)(bcol + 64 * (q0 >> 3) + r) * K + (q0 & 7) * 8;
  }

#define G_STAGE(BUF)                                                      \
  {                                                                       \
    _Pragma("unroll") for (int i = 0; i < 4; ++i) {                       \
      GLOAD_LDS16(pA[i], As + (BUF) * 16384 + i * 4096 + w * 512);        \
      pA[i] += 64;                                                        \
    }                                                                     \
    _Pragma("unroll") for (int i = 0; i < 2; ++i) {                       \
      GLOAD_LDS16(pB[i], Bs + (BUF) * 8192 + i * 4096 + w * 512);         \
      pB[i] += 64;                                                        \
    }                                                                     \
  }

  floatx4 acc[4][4] = {};

  // A-frag (m,ks): row ar = wm*64+m*16+l16 -> half wm>>1, g = wm&1, r = m*16+l16
  //   byte = (wm>>1)*16384 + (m*16+l16)*256 + (((wm&1)*8 + ks*4 + lhi) ^ l16)*16
  // B-frag (n,ks): byte = (n*16+l16)*256 + ((wn*8 + ks*4 + lhi) ^ l16)*16
#define G_COMPUTE(BUF)                                                               \
  {                                                                                  \
    short8 a[4][2], b[4][2];                                                         \
    _Pragma("unroll") for (int m = 0; m < 4; ++m)                                    \
      _Pragma("unroll") for (int ks = 0; ks < 2; ++ks)                               \
        a[m][ks] = *(const short8*)((const char*)(As + (BUF) * 16384) +              \
            (wm >> 1) * 16384 +                                                      \
            (m * 16 + l16) * 256 + ((((wm & 1) * 8 + ks * 4 + lhi) ^ l16) << 4));    \
    _Pragma("unroll") for (int n = 0; n < 4; ++n)                                    \
      _Pragma("unroll") for (int ks = 0; ks < 2; ++ks)                               \
        b[n][ks] = *(const short8*)((const char*)(Bs + (BUF) * 8192) +               \
            (n * 16 + l16) * 256 + (((wn * 8 + ks * 4 + lhi) ^ l16) << 4));          \
    _Pragma("unroll") for (int ks = 0; ks < 2; ++ks)                                 \
      _Pragma("unroll") for (int m = 0; m < 4; ++m)                                  \
        _Pragma("unroll") for (int n = 0; n < 4; ++n)                                \
          acc[m][n] = MFMA16(a[m][ks], b[n][ks], acc[m][n]);                         \
  }

#define G_STEP(RD, ST)   \
  {                      \
    G_STAGE(ST);         \
    G_COMPUTE(RD);       \
    WAITVM(6);           \
    SBAR;                \
  }

  // prologue: stage kt=0,1; wait kt0 resident (6 of 12 oldest)
  G_STAGE(0);
  G_STAGE(1);
  WAITVM(6);
  SBAR;

  // kt = 0..11 (stage kt+2 = 2..13)
#pragma unroll 1
  for (int g = 0; g < 4; ++g) {
    G_STEP(0, 2);
    G_STEP(1, 0);
    G_STEP(2, 1);
  }
  G_STEP(0, 2);   // kt=12, stage 14
  G_STEP(1, 0);   // kt=13, stage 15
  // kt=14: no more staging; drain kt15's loads
  G_COMPUTE(2);
  WAITVM(0);
  SBAR;
  // kt=15
  G_COMPUTE(0);

  // ---- epilogue ----
#pragma unroll
  for (int n = 0; n < 4; ++n) {
    int col = bcol + wn * 64 + n * 16 + l16;
    float bv = bias[col];
    if (MODE == 2) {
      int h = col >> 6, d = col & 63;
#pragma unroll
      for (int m = 0; m < 4; ++m) {
        int row = brow + wm * 64 + m * 16 + lhi * 4;   // j=0 row
        int b_ = row >> 11, s = row & 2047;
        union { uint16_t u[4]; ushort4v v; } pk4;
#pragma unroll
        for (int j = 0; j < 4; ++j) pk4.u[j] = f2bf(acc[m][n][j] + bv);
        *(ushort4v*)((uint16_t*)Cout + (size_t)(b_ * 16 + h) * 131072 + (size_t)d * 2048 + s) = pk4.v;
      }
    } else {
#pragma unroll
      for (int m = 0; m < 4; ++m) {
#pragma unroll
        for (int j = 0; j < 4; ++j) {
          int row = brow + wm * 64 + m * 16 + lhi * 4 + j;
          float v = (acc[m][n][j] + bv) * scale;
          if (MODE == 1)
            ((uint16_t*)Cout)[(size_t)row * N + col] = f2bf(v);
          else
            ((float*)Cout)[(size_t)row * N + col] = v;
        }
      }
    }
  }
#undef G_STAGE
#undef G_COMPUTE
#undef G_STEP
}

// fused Q/K/V projections: 768 blocks (8x, 32y, 3z), XCD-chunked; V pre-transposed.
__global__ __launch_bounds__(512, 1)
void gemm_qkv_k(const uint16_t* __restrict__ XQ, const uint16_t* __restrict__ XK,
                const uint16_t* __restrict__ XV, const uint16_t* __restrict__ WQ,
                const uint16_t* __restrict__ WK, const uint16_t* __restrict__ WV,
                const float* __restrict__ bq, const float* __restrict__ bk,
                const float* __restrict__ bv, uint16_t* __restrict__ QP,
                uint16_t* __restrict__ KP, uint16_t* __restrict__ VT, float qscale) {
  __shared__ uint16_t As[3 * 16384];   // 96KB
  __shared__ uint16_t Bs[3 * 8192];    // 48KB
  const int f = (blockIdx.z * 32 + blockIdx.y) * 8 + blockIdx.x;
  const int virt = (f & 7) * 96 + (f >> 3);     // 768 = 8*96, bijective
  const int vz = virt >> 8;
  const int rem = virt & 255;
  const int vy = rem >> 3, vx = rem & 7;

  if (vz == 0)      gemm256_body<1>(As, Bs, XQ, WQ, bq, QP, qscale, vy * 256, vx * 128);
  else if (vz == 1) gemm256_body<1>(As, Bs, XK, WK, bk, KP, 1.0f,  vy * 256, vx * 128);
  else              gemm256_body<2>(As, Bs, XV, WV, bv, VT, 1.0f,  vy * 256, vx * 128);
}

// output projection: 256 blocks (8x, 32y), XCD-chunked.
__global__ __launch_bounds__(512, 1)
void gemm_o_k(const uint16_t* __restrict__ A, const uint16_t* __restrict__ W,
              const float* __restrict__ bias, float* __restrict__ Cout) {
  __shared__ uint16_t As[3 * 16384];
  __shared__ uint16_t Bs[3 * 8192];
  const int f = blockIdx.y * 8 + blockIdx.x;
  const int virt = (f & 7) * 32 + (f >> 3);
  const int vy = virt >> 3, vx = virt & 7;
  gemm256_body<0>(As, Bs, A, W, bias, Cout, 1.0f, vy * 256, vx * 128);
}

// ---------- flash attention: quarter-pipelined (QK_next ∥ exp/pack_cur) ----------
__global__ __launch_bounds__(512, 2)
void attn_k(const uint16_t* __restrict__ Qp, const uint16_t* __restrict__ Kp,
            const uint16_t* __restrict__ Vt, uint16_t* __restrict__ AO) {
  __shared__ uint16_t Kl[2][64 * 128];   // 16KB per buffer
  __shared__ uint16_t Vl[2][64 * 128];   // 16KB per buffer

  const int t = threadIdx.x;
  const int l = t & 63, w = t >> 6;       // w = 0..7
  const int l32 = l & 31, hi = l >> 5;

  // XCD-chunked swizzle: 512 blocks, 64 per XCD -> 8 contiguous bh groups each.
  const int f = blockIdx.y * 8 + blockIdx.x;
  const int virt = (f & 7) * 64 + (f >> 3);
  const int vx = virt & 7;     // q-block (256 q each)
  const int vy = virt >> 3;    // bh

  const int q0 = vx * 256 + w * 32;
  const size_t base = (size_t)(vy >> 4) * 2048 * 1024 + (size_t)(vy & 15) * 64;
  const size_t vbg = (size_t)vy * 131072;  // (b*16+h)*64*2048

  union PAu { uint32_t u[4]; short8 s; };

  // staging: 1024 chunks per matrix per tile; 512 threads -> 2 issues each.
  const uint16_t* pK[2];
  const uint16_t* pV[2];
#pragma unroll
  for (int i = 0; i < 2; ++i) {
    int c = i * 512 + t;
    int r = c >> 4, qs = c & 15;
    int q0c = qs ^ (r & 15);
    pK[i] = Kp + base + (size_t)(64 * (q0c >> 3) + r) * 1024 + (q0c & 7) * 8;
    pV[i] = Vt + vbg + (size_t)r * 2048 + q0c * 8;
  }

#define STAGE_ALL(NB)                                                 \
  {                                                                   \
    _Pragma("unroll") for (int i = 0; i < 2; ++i) {                   \
      GLOAD_LDS16(pK[i], &Kl[NB][(size_t)(i * 512 + w * 64) * 8]);    \
      GLOAD_LDS16(pV[i], &Vl[NB][(size_t)(i * 512 + w * 64) * 8]);    \
      pK[i] += 131072;  /* +128 source rows */                        \
      pV[i] += 128;     /* +128 s columns  */                        \
    }                                                                 \
  }

  // Q B-frags: lane holds Q[q0 + l32][k = ks*16 + hi*8 + i]
  short8 qf[4];
#pragma unroll
  for (int ks = 0; ks < 4; ++ks)
    qf[ks] = *(const short8*)(Qp + base + (size_t)(q0 + l32) * 1024 + ks * 16 + hi * 8);

  floatx16 of0 = {}, of1 = {};   // O[q][d] C-frags
  float rs = 0.f;                // per-lane partial rowsum

  const int swzb = (l32 & 15);
  const int krow = l32 * 256;    // byte base of LDS row l32 (row +32 = +8192)

  STAGE_ALL(0);
  __syncthreads();

#define QK_Q(SF, CUR, H, RH)                                                          \
  {                                                                                   \
    _Pragma("unroll") for (int ks = 0; ks < 4; ++ks) {                                \
      int kbyte = krow + (RH) * 8192 + ((((H) * 8 + 2 * ks + hi) ^ swzb) << 4);       \
      short8 kf = *(const short8*)((char*)Kl[CUR] + kbyte);                           \
      SF = MFMA32(kf, qf[ks], SF);                                                    \
    }                                                                                 \
  }

#define EXPPACK(SF, P0, P1)                                                           \
  {                                                                                   \
    _Pragma("unroll") for (int r = 0; r < 16; ++r) {                                  \
      SF[r] = __builtin_amdgcn_exp2f(SF[r]);                                          \
      rs += SF[r];                                                                    \
    }                                                                                 \
    uint32_t a0, a1, b0, b1;                                                          \
    CVTPK(SF[0], SF[1], a0); CVTPK(SF[2], SF[3], a1);                                 \
    CVTPK(SF[4], SF[5], b0); CVTPK(SF[6], SF[7], b1);                                 \
    SWAP32(a0, b0); SWAP32(a1, b1);                                                   \
    P0.u[0] = a0; P0.u[1] = a1; P0.u[2] = b0; P0.u[3] = b1;                           \
    CVTPK(SF[8], SF[9], a0); CVTPK(SF[10], SF[11], a1);                               \
    CVTPK(SF[12], SF[13], b0); CVTPK(SF[14], SF[15], b1);                             \
    SWAP32(a0, b0); SWAP32(a1, b1);                                                   \
    P1.u[0] = a0; P1.u[1] = a1; P1.u[2] = b0; P1.u[3] = b1;                           \
  }

#define PV_Q(P0, P1, CUR, H, RH)                                                      \
  {                                                                                   \
    int vb0 = krow + ((((H) * 8 + 2 * (2 * (RH)) + hi) ^ swzb) << 4);                 \
    int vb1 = krow + ((((H) * 8 + 2 * (2 * (RH) + 1) + hi) ^ swzb) << 4);             \
    short8 vf00 = *(const short8*)((char*)Vl[CUR] + vb0);                             \
    short8 vf01 = *(const short8*)((char*)Vl[CUR] + vb0 + 8192);                      \
    short8 vf10 = *(const short8*)((char*)Vl[CUR] + vb1);                             \
    short8 vf11 = *(const short8*)((char*)Vl[CUR] + vb1 + 8192);                      \
    of0 = MFMA32(P0.s, vf00, of0);                                                    \
    of1 = MFMA32(P0.s, vf01, of1);                                                    \
    of0 = MFMA32(P1.s, vf10, of0);                                                    \
    of1 = MFMA32(P1.s, vf11, of1);                                                    \
  }

#define STEP128(CUR, PF)                                                              \
  {                                                                                   \
    if (PF) STAGE_ALL(CUR ^ 1);                                                       \
    floatx16 sfA = {}, sfB = {};                                                      \
    QK_Q(sfA, CUR, 0, 0);                                                             \
    QK_Q(sfB, CUR, 0, 1);                                                             \
    {                                                                                 \
      PAu p0, p1;                                                                     \
      EXPPACK(sfA, p0, p1);                                                           \
      PV_Q(p0, p1, CUR, 0, 0);                                                        \
    }                                                                                 \
    sfA = (floatx16){};                                                               \
    QK_Q(sfA, CUR, 1, 0);                                                             \
    {                                                                                 \
      PAu p0, p1;                                                                     \
      EXPPACK(sfB, p0, p1);                                                           \
      PV_Q(p0, p1, CUR, 0, 1);                                                        \
    }                                                                                 \
    sfB = (floatx16){};                                                               \
    QK_Q(sfB, CUR, 1, 1);                                                             \
    {                                                                                 \
      PAu p0, p1;                                                                     \
      EXPPACK(sfA, p0, p1);                                                           \
      PV_Q(p0, p1, CUR, 1, 0);                                                        \
    }                                                                                 \
    {                                                                                 \
      PAu p0, p1;                                                                     \
      EXPPACK(sfB, p0, p1);                                                           \
      PV_Q(p0, p1, CUR, 1, 1);                                                        \
    }                                                                                 \
    __syncthreads();                                                                  \
  }

  for (int it = 0; it < 8; ++it) {   // 16 kv-tiles of 128, 2 per iteration
    STEP128(0, 1);
    STEP128(1, it < 7);
  }

  // --- epilogue: complete rowsums and normalize.
  rs += __shfl_xor(rs, 32);          // full rowsum for q = l32 (both hi halves)
#pragma unroll
  for (int r = 0; r < 16; ++r) {
    int qloc = (r & 3) + 8 * (r >> 2) + 4 * hi;       // q index of of-frag row r
    float rsq = __shfl(rs, qloc);                      // rowsum for that q
    float rinv = 1.0f / rsq;
    int qrow = q0 + qloc;
    AO[base + (size_t)qrow * 1024 + l32]      = f2bf(of0[r] * rinv);
    AO[base + (size_t)qrow * 1024 + 32 + l32] = f2bf(of1[r] * rinv);
  }
#undef STAGE_ALL
#undef QK_Q
#undef EXPPACK
#undef PV_Q
#undef STEP128
}

// ---------- launch ----------
extern "C" void kernel_launch(void* const* d_in, const int* in_sizes, int n_in,
                              void* d_out, int out_size, void* d_ws, size_t ws_size,
                              hipStream_t stream) {
  const float* q  = (const float*)d_in[0];
  const float* k  = (const float*)d_in[1];
  const float* v  = (const float*)d_in[2];
  const float* Wq = (const float*)d_in[3];
  const float* bq = (const float*)d_in[4];
  const float* Wk = (const float*)d_in[5];
  const float* bk = (const float*)d_in[6];
  const float* Wv = (const float*)d_in[7];
  const float* bv = (const float*)d_in[8];
  const float* Wo = (const float*)d_in[9];
  const float* bo = (const float*)d_in[10];

  const size_t MB = 1ull << 20;
  char* ws = (char*)d_ws;
  uint16_t* XQ  = (uint16_t*)(ws + 0 * MB);    // 16MB x3, contiguous (cvt3 strides)
  uint16_t* XK  = (uint16_t*)(ws + 16 * MB);
  uint16_t* XV  = (uint16_t*)(ws + 32 * MB);
  uint16_t* WQb = (uint16_t*)(ws + 48 * MB);   // 2MB x4, contiguous (cvt4 strides)
  uint16_t* WKb = (uint16_t*)(ws + 50 * MB);
  uint16_t* WVb = (uint16_t*)(ws + 52 * MB);
  uint16_t* WOb = (uint16_t*)(ws + 54 * MB);
  uint16_t* QP  = (uint16_t*)(ws + 56 * MB);
  uint16_t* KP  = (uint16_t*)(ws + 72 * MB);
  uint16_t* VT  = (uint16_t*)(ws + 88 * MB);   // V projected + transposed, 16MB
  uint16_t* AO  = XQ;   // alias: XQ dead after QKV projection

  const int NTOK = 4 * 2048;
  const int D = 1024;
  const int nBig = NTOK * D / 4;  // 2M float4
  const int nW = D * D / 4;       // 256K float4
  const float qscale = 0.125f * 1.4426950408889634f;  // softmax scale * log2e -> exp2

  cvt3_k<<<dim3(2048, 1, 3), dim3(256), 0, stream>>>(q, k, v, XQ, nBig);
  cvt4_k<<<dim3(1024, 1, 4), dim3(256), 0, stream>>>(Wq, Wk, Wv, Wo, WQb, nW);

  gemm_qkv_k<<<dim3(8, 32, 3), dim3(512), 0, stream>>>(
      XQ, XK, XV, WQb, WKb, WVb, bq, bk, bv, QP, KP, VT, qscale);

  attn_k<<<dim3(8, 64), dim3(512), 0, stream>>>(QP, KP, VT, AO);

  gemm_o_k<<<dim3(8, 32), dim3(512), 0, stream>>>(AO, WOb, bo, (float*)d_out);
}